// Round 2
// baseline (780.020 us; speedup 1.0000x reference)
//
#include <hip/hip_runtime.h>

// ---------------- problem dims ----------------
#define NE   200000
#define DC   64
#define DL   256
#define DD   128
#define FEAT 320          // 2*DD + DC
#define IND  449          // FEAT + DD + 1
#define DH   80
#define BB   32
#define TT   64
#define NEV  2048         // BB*TT
#define NSLOT 4096

typedef __attribute__((ext_vector_type(4))) float  floatx4;

__device__ __forceinline__ float sigmoidf_(float x) { return 1.0f / (1.0f + __expf(-x)); }

// ---------------- K1: slot analysis (prev-toucher, dt, winner) ----------------
// slot = t*64 + side*32 + b  (key order = scatter order: later step > o > s > higher b)
// Wave-parallel: one 64-lane wave per slot; lane l scans j = jj*64+l (bank-conflict-free),
// then butterfly max-reduce for `best`, __all for `win`.
__global__ __launch_bounds__(256)
void slot_analyze(const int* __restrict__ seq_s, const int* __restrict__ seq_o,
                  const float* __restrict__ seq_time, const float* __restrict__ lt0,
                  float* __restrict__ slotDt, int* __restrict__ slotPrev,
                  int* __restrict__ slotWin) {
    __shared__ int entL[NSLOT];
    int tid = threadIdx.x;
    for (int j = tid; j < NSLOT; j += 256) {
        int b = j & 31, side = (j >> 5) & 1, t = j >> 6;
        entL[j] = (side ? seq_o : seq_s)[b * TT + t];
    }
    __syncthreads();
    int wave = tid >> 6, lane = tid & 63;
    int slot = blockIdx.x * 4 + wave;
    int t = slot >> 6;
    int myent = entL[slot];
    int win = 1, best = -1;
#pragma unroll 8
    for (int jj = 0; jj < NSLOT / 64; ++jj) {
        int j = jj * 64 + lane;
        if (entL[j] == myent) {
            if (j > slot) win = 0;
            else if ((j >> 6) < t && j > best) best = j;   // keeps max key among prior steps
        }
    }
    // wave all-reduce: max over best
#pragma unroll
    for (int off = 32; off; off >>= 1) {
        int ob = __shfl_xor(best, off, 64);
        best = best > ob ? best : ob;
    }
    win = __all(win);
    if (lane == 0) {
        int b = slot & 31;
        float tv = seq_time[b * TT + t];
        float pt = (best >= 0) ? seq_time[(best & 31) * TT + (best >> 6)] : lt0[myent];
        slotDt[slot]   = tv - pt;
        slotPrev[slot] = best;
        slotWin[slot]  = win;
    }
}

// ---------------- K1b: build fix list (events whose s- or o-input has a prior toucher) ----
__global__ __launch_bounds__(256)
void fixlist_build(const int* __restrict__ slotPrev, int* __restrict__ fixList,
                   int* __restrict__ fixState, int* __restrict__ evFixIdx,
                   int* __restrict__ fixCnt) {
    int e = blockIdx.x * 256 + threadIdx.x;   // 2048 events
    int b = e >> 6, t = e & 63;
    int c = (slotPrev[t * 64 + b] >= 0) | (slotPrev[t * 64 + 32 + b] >= 0);
    int idx = -1;
    if (c) { idx = atomicAdd(fixCnt, 1); fixList[idx] = e; fixState[idx] = -1; }
    evFixIdx[e] = idx;
}

// ---------------- K2: all-events parallel RNN compute (fp32) ----------------
__global__ __launch_bounds__(256)
void event_compute(const int* __restrict__ seq_s, const int* __restrict__ seq_o,
                   const int* __restrict__ seq_r, const float* __restrict__ seq_time,
                   const float* __restrict__ mem0, const float* __restrict__ rel,
                   const float* __restrict__ W_hidden, const float* __restrict__ W_hh,
                   const float* __restrict__ W_st, const float* __restrict__ W_ot,
                   const float* __restrict__ slotDt,
                   float* __restrict__ evt, float* __restrict__ ebuf,
                   float* __restrict__ tebuf) {
    __shared__ float xc[8][FEAT];
    __shared__ float hs[8][DL];
    __shared__ int   sSi[8], sOi[8], sRi[8];
    __shared__ float sDs[8], sDo[8], sTv[8];
    int tid = threadIdx.x;
    int e0 = blockIdx.x * 8;
    if (tid < 8) {
        int e = e0 + tid;
        sSi[tid] = seq_s[e]; sOi[tid] = seq_o[e]; sRi[tid] = seq_r[e];
        int b = e >> 6, t = e & 63;
        sDs[tid] = slotDt[t * 64 + b];
        sDo[tid] = slotDt[t * 64 + 32 + b];
        sTv[tid] = seq_time[e];
    }
    __syncthreads();
    for (int i = tid; i < 8 * FEAT; i += 256) {
        int r = i / FEAT, k = i - r * FEAT;
        float v;
        if (k < DD)            v = mem0[(size_t)sSi[r] * DD + k];
        else if (k < 2 * DD)   v = mem0[(size_t)sOi[r] * DD + (k - DD)];
        else                   v = rel[(size_t)sRi[r] * DC + (k - 2 * DD)];
        xc[r][k] = v;
    }
    __syncthreads();
    {   // z = xc @ W_hidden ; h = sigmoid(z)
        int j = tid;
        float acc[8] = {0.f,0.f,0.f,0.f,0.f,0.f,0.f,0.f};
        for (int k = 0; k < FEAT; ++k) {
            float w = W_hidden[(size_t)k * DL + j];
#pragma unroll
            for (int r = 0; r < 8; ++r) acc[r] += xc[r][k] * w;
        }
#pragma unroll
        for (int r = 0; r < 8; ++r) hs[r][j] = sigmoidf_(acc[r]);
    }
    __syncthreads();
    {   // hh = h @ W_hh ; ns/no = sigmoid(dt*W + hh)
        int d = tid & 127, grp = tid >> 7;     // grp 0 -> events 0..3, grp 1 -> 4..7
        float acc[4] = {0.f,0.f,0.f,0.f};
        for (int l = 0; l < DL; ++l) {
            float w = W_hh[(size_t)l * DD + d];
#pragma unroll
            for (int rr = 0; rr < 4; ++rr) acc[rr] += hs[grp * 4 + rr][l] * w;
        }
        float wst = W_st[d], wot = W_ot[d];
#pragma unroll
        for (int rr = 0; rr < 4; ++rr) {
            int r = grp * 4 + rr;
            int e = e0 + r;
            float ns  = sigmoidf_(sDs[r] * wst + acc[rr]);
            float no_ = sigmoidf_(sDo[r] * wot + acc[rr]);
            evt[(size_t)e * FEAT + d]      = ns;
            evt[(size_t)e * FEAT + DD + d] = no_;
            ebuf[(size_t)e * IND + d]      = ns;
            ebuf[(size_t)e * IND + DD + d] = no_;
        }
    }
    // rel section + time_emb + ones
    for (int i = tid; i < 8 * DC; i += 256) {
        int r = i >> 6, c = i & 63;
        float v = xc[r][2 * DD + c];
        int e = e0 + r;
        evt[(size_t)e * FEAT + 2 * DD + c] = v;
        ebuf[(size_t)e * IND + 2 * DD + c] = v;
    }
    for (int i = tid; i < 8 * DD; i += 256) {
        int r = i >> 7, d = i & 127;
        float denom = __powf(1.0e4f, (float)d);     // inf for d>=10 -> 1/inf = 0 (matches ref)
        float v = sinf(sTv[r] * (1.0f / denom));
        int e = e0 + r;
        ebuf[(size_t)e * IND + FEAT + d] = v;
        tebuf[(size_t)e * DD + d] = v;
    }
    if (tid < 8) ebuf[(size_t)(e0 + tid) * IND + FEAT + DD] = 1.0f;
}

// ---------------- K3: fix rounds (collision events, dependency-ordered) ----------------
__global__ __launch_bounds__(256)
void fix_round(int round,
               const int* __restrict__ seq_s, const int* __restrict__ seq_o,
               const float* __restrict__ mem0, const float* __restrict__ W_hidden,
               const float* __restrict__ W_hh, const float* __restrict__ W_st,
               const float* __restrict__ W_ot, const float* __restrict__ slotDt,
               const int* __restrict__ slotPrev, const int* __restrict__ fixList,
               int* __restrict__ fixState, const int* __restrict__ evFixIdx,
               const int* __restrict__ fixCnt,
               float* __restrict__ evt, float* __restrict__ ebuf) {
    __shared__ float xc[FEAT];
    __shared__ float hsv[DL];
    __shared__ float hp[2][DD];
    __shared__ int sGo, sPs, sPo, sE;
    int tid = threadIdx.x;
    int n = *fixCnt;
    for (int f = blockIdx.x; f < n; f += gridDim.x) {
        if (tid == 0) {
            int go = 0, ps = 0, po = 0, e = 0;
            if (fixState[f] == -1) {
                e = fixList[f];
                int b = e >> 6, t = e & 63;
                ps = slotPrev[t * 64 + b];
                po = slotPrev[t * 64 + 32 + b];
                go = 1;
                if (ps >= 0) {
                    int pe = (ps & 31) * 64 + (ps >> 6);
                    int fi = evFixIdx[pe];
                    if (fi >= 0) { int st = fixState[fi]; if (st < 0 || st >= round) go = 0; }
                }
                if (po >= 0) {
                    int pe = (po & 31) * 64 + (po >> 6);
                    int fi = evFixIdx[pe];
                    if (fi >= 0) { int st = fixState[fi]; if (st < 0 || st >= round) go = 0; }
                }
            }
            sGo = go; sPs = ps; sPo = po; sE = e;
        }
        __syncthreads();
        int go = sGo, ps = sPs, po = sPo, e = sE;
        __syncthreads();
        if (!go) continue;
        int b = e >> 6, t = e & 63;
        // gather current inputs
        for (int i = tid; i < FEAT; i += 256) {
            float v;
            if (i < DD) {
                v = (ps >= 0) ? evt[(size_t)((ps & 31) * 64 + (ps >> 6)) * FEAT + ((ps >> 5) & 1) * DD + i]
                              : mem0[(size_t)seq_s[e] * DD + i];
            } else if (i < 2 * DD) {
                int k = i - DD;
                v = (po >= 0) ? evt[(size_t)((po & 31) * 64 + (po >> 6)) * FEAT + ((po >> 5) & 1) * DD + k]
                              : mem0[(size_t)seq_o[e] * DD + k];
            } else {
                v = evt[(size_t)e * FEAT + i];    // rel section (unchanged by fixes)
            }
            xc[i] = v;
        }
        __syncthreads();
        {   // z GEMV with 4-way ILP
            float a0 = 0.f, a1 = 0.f, a2 = 0.f, a3 = 0.f;
            for (int k = 0; k < FEAT; k += 4) {
                a0 += xc[k]     * W_hidden[(size_t)k * DL + tid];
                a1 += xc[k + 1] * W_hidden[(size_t)(k + 1) * DL + tid];
                a2 += xc[k + 2] * W_hidden[(size_t)(k + 2) * DL + tid];
                a3 += xc[k + 3] * W_hidden[(size_t)(k + 3) * DL + tid];
            }
            hsv[tid] = sigmoidf_((a0 + a1) + (a2 + a3));
        }
        __syncthreads();
        {   // hh partials
            int d = tid & 127, g = tid >> 7;
            float a0 = 0.f, a1 = 0.f;
            int l0 = g * 128;
            for (int l = 0; l < 128; l += 2) {
                a0 += hsv[l0 + l]     * W_hh[(size_t)(l0 + l) * DD + d];
                a1 += hsv[l0 + l + 1] * W_hh[(size_t)(l0 + l + 1) * DD + d];
            }
            hp[g][d] = a0 + a1;
        }
        __syncthreads();
        if (tid < DD) {
            float hh = hp[0][tid] + hp[1][tid];
            float ns  = sigmoidf_(slotDt[t * 64 + b]      * W_st[tid] + hh);
            float no_ = sigmoidf_(slotDt[t * 64 + 32 + b] * W_ot[tid] + hh);
            evt[(size_t)e * FEAT + tid]      = ns;
            evt[(size_t)e * FEAT + DD + tid] = no_;
            ebuf[(size_t)e * IND + tid]      = ns;
            ebuf[(size_t)e * IND + DD + tid] = no_;
        }
        __syncthreads();
        __threadfence();
        if (tid == 0) fixState[f] = round;
        __syncthreads();
    }
}

// ---------------- K4: winner scatter to out_mem / out_lt ----------------
__global__ __launch_bounds__(256)
void scatter_win(const int* __restrict__ seq_s, const int* __restrict__ seq_o,
                 const float* __restrict__ seq_time, const int* __restrict__ slotWin,
                 const float* __restrict__ evt, float* __restrict__ out_mem,
                 float* __restrict__ out_lt) {
    int gid = blockIdx.x * 256 + threadIdx.x;   // 131072 = 4096 slots * 32
    int slot = gid >> 5, c = gid & 31;
    if (!slotWin[slot]) return;
    int b = slot & 31, side = (slot >> 5) & 1, t = slot >> 6;
    int e = b * TT + t;
    int ent = (side ? seq_o : seq_s)[e];
    floatx4 v = *(const floatx4*)&evt[(size_t)e * FEAT + side * DD + c * 4];
    *(floatx4*)&out_mem[(size_t)ent * DD + c * 4] = v;
    if (c == 0) out_lt[ent] = seq_time[e];
}

// ---------------- phase 2: tiled GEMMs ----------------
// proj: C[2048][320] = A[2048][449(IND)] @ W[449][320], for z in {q,k,v}.
// BM=64, BN=64, BK=32; 256 threads, each 4 rows x 4 cols.
__global__ __launch_bounds__(256)
void proj(const float* __restrict__ ebuf, const float* __restrict__ Wq,
          const float* __restrict__ Wk, const float* __restrict__ Wv,
          float* __restrict__ q, float* __restrict__ k, float* __restrict__ v) {
    __shared__ float As[64][33];
    __shared__ float Bs[32][68];
    const float* W = (blockIdx.z == 0) ? Wq : (blockIdx.z == 1) ? Wk : Wv;
    float* out = (blockIdx.z == 0) ? q : (blockIdx.z == 1) ? k : v;
    int tid = threadIdx.x;
    int row0 = blockIdx.x * 64;
    int col0 = blockIdx.y * 64;
    int tx = tid & 15, ty = tid >> 4;
    floatx4 acc[4];
#pragma unroll
    for (int i = 0; i < 4; ++i) acc[i] = (floatx4){0.f, 0.f, 0.f, 0.f};
    for (int k0 = 0; k0 < IND; k0 += 32) {
        for (int i = tid; i < 64 * 32; i += 256) {          // stage A (coalesced along k)
            int r = i >> 5, kk = i & 31;
            int kg = k0 + kk;
            As[r][kk] = (kg < IND) ? ebuf[(size_t)(row0 + r) * IND + kg] : 0.f;
        }
        for (int i = tid; i < 32 * 64; i += 256) {          // stage B (coalesced along n)
            int kk = i >> 6, c = i & 63;
            int kg = k0 + kk;
            Bs[kk][c] = (kg < IND) ? W[(size_t)kg * FEAT + col0 + c] : 0.f;
        }
        __syncthreads();
#pragma unroll 8
        for (int kk = 0; kk < 32; ++kk) {
            floatx4 b = *(const floatx4*)&Bs[kk][tx * 4];
            float a0 = As[ty * 4 + 0][kk];
            float a1 = As[ty * 4 + 1][kk];
            float a2 = As[ty * 4 + 2][kk];
            float a3 = As[ty * 4 + 3][kk];
            acc[0] += a0 * b;
            acc[1] += a1 * b;
            acc[2] += a2 * b;
            acc[3] += a3 * b;
        }
        __syncthreads();
    }
#pragma unroll
    for (int i = 0; i < 4; ++i)
        *(floatx4*)&out[(size_t)(row0 + ty * 4 + i) * FEAT + col0 + tx * 4] = acc[i];
}

// outproj: acc = A[2048][320] @ Wo[320][320]; x = resid + tanh(acc); optional ebuf write.
__global__ __launch_bounds__(256)
void outproj(const float* __restrict__ ain, const float* __restrict__ Wo,
             const float* __restrict__ resid, float* __restrict__ xout,
             float* __restrict__ ebufW, int writeE) {
    __shared__ float As[64][33];
    __shared__ float Bs[32][68];
    int tid = threadIdx.x;
    int row0 = blockIdx.x * 64;
    int col0 = blockIdx.y * 64;
    int tx = tid & 15, ty = tid >> 4;
    floatx4 acc[4];
#pragma unroll
    for (int i = 0; i < 4; ++i) acc[i] = (floatx4){0.f, 0.f, 0.f, 0.f};
    for (int k0 = 0; k0 < FEAT; k0 += 32) {
        for (int i = tid; i < 64 * 32; i += 256) {
            int r = i >> 5, kk = i & 31;
            As[r][kk] = ain[(size_t)(row0 + r) * FEAT + k0 + kk];
        }
        for (int i = tid; i < 32 * 64; i += 256) {
            int kk = i >> 6, c = i & 63;
            Bs[kk][c] = Wo[(size_t)(k0 + kk) * FEAT + col0 + c];
        }
        __syncthreads();
#pragma unroll 8
        for (int kk = 0; kk < 32; ++kk) {
            floatx4 b = *(const floatx4*)&Bs[kk][tx * 4];
            float a0 = As[ty * 4 + 0][kk];
            float a1 = As[ty * 4 + 1][kk];
            float a2 = As[ty * 4 + 2][kk];
            float a3 = As[ty * 4 + 3][kk];
            acc[0] += a0 * b;
            acc[1] += a1 * b;
            acc[2] += a2 * b;
            acc[3] += a3 * b;
        }
        __syncthreads();
    }
#pragma unroll
    for (int i = 0; i < 4; ++i) {
        int row = row0 + ty * 4 + i;
        int c0 = col0 + tx * 4;
        floatx4 res = *(const floatx4*)&resid[(size_t)row * FEAT + c0];
        floatx4 o;
#pragma unroll
        for (int j = 0; j < 4; ++j) o[j] = res[j] + tanhf(acc[i][j]);
        *(floatx4*)&xout[(size_t)row * FEAT + c0] = o;
        if (writeE) {
#pragma unroll
            for (int j = 0; j < 4; ++j) ebufW[(size_t)row * IND + c0 + j] = o[j];
        }
    }
}

__global__ __launch_bounds__(256)
void attn(const float* __restrict__ q, const float* __restrict__ k,
          const float* __restrict__ v, float* __restrict__ ao) {
    __shared__ float qs[TT][DH], ks[TT][DH], vs[TT][DH];
    __shared__ float sc[TT][TT + 1];
    int bh = blockIdx.x;
    int b = bh >> 2, h = bh & 3;
    int tid = threadIdx.x;
    for (int i = tid; i < TT * DH; i += 256) {
        int r = i / DH, d = i - r * DH;
        size_t base = (size_t)(b * TT + r) * FEAT + h * DH + d;
        qs[r][d] = q[base]; ks[r][d] = k[base]; vs[r][d] = v[base];
    }
    __syncthreads();
    const float scale = 0.11180339887498949f;   // 1/sqrt(80)
    for (int idx = tid; idx < TT * TT; idx += 256) {
        int i = idx >> 6, j = idx & 63;
        float s = 0.f;
        for (int d = 0; d < DH; ++d) s += qs[i][d] * ks[j][d];
        sc[i][j] = s * scale;
    }
    __syncthreads();
    if (tid < TT) {
        int i = tid;
        if (i == 0) {
            for (int j = 0; j < TT; ++j) sc[0][j] = 0.0f;
        } else {
            float m = -1e30f;
            for (int j = 0; j < i; ++j) m = fmaxf(m, sc[i][j]);
            float sum = 0.f;
            for (int j = 0; j < i; ++j) { float p = __expf(sc[i][j] - m); sc[i][j] = p; sum += p; }
            float inv = 1.0f / sum;
            for (int j = 0; j < i; ++j) sc[i][j] *= inv;
            for (int j = i; j < TT; ++j) sc[i][j] = 0.0f;
        }
    }
    __syncthreads();
    for (int idx = tid; idx < TT * DH; idx += 256) {
        int i = idx / DH, d = idx - i * DH;
        float s = 0.f;
        for (int j = 0; j < TT; ++j) s += sc[i][j] * vs[j][d];
        ao[(size_t)(b * TT + i) * FEAT + h * DH + d] = s;
    }
}

__global__ __launch_bounds__(128)
void score_k(const float* __restrict__ x, const float* __restrict__ W1,
             const float* __restrict__ b1, const float* __restrict__ W2,
             const float* __restrict__ b2, float* __restrict__ lam_out,
             float* __restrict__ loss_out) {
    __shared__ float xr[FEAT];
    __shared__ float red[2];
    int e = blockIdx.x;
    int tid = threadIdx.x;
    for (int f = tid; f < FEAT; f += 128) xr[f] = x[(size_t)e * FEAT + f];
    __syncthreads();
    int d = tid;
    float acc = b1[d];
    for (int kk = 0; kk < FEAT; ++kk) acc += xr[kk] * W1[kk * DD + d];
    acc = fmaxf(acc, 0.0f) * W2[d];
    for (int off = 32; off; off >>= 1) acc += __shfl_down(acc, off, 64);
    if ((tid & 63) == 0) red[tid >> 6] = acc;
    __syncthreads();
    if (tid == 0) {
        float s = red[0] + red[1] + b2[0];
        float lam = fmaxf(s, 0.0f) + log1pf(expf(-fabsf(s)));   // softplus
        lam_out[e] = lam;
        atomicAdd(loss_out, -logf(lam + 1e-8f) * (1.0f / 2048.0f));
    }
}

// ---------------- launch ----------------
extern "C" void kernel_launch(void* const* d_in, const int* in_sizes, int n_in,
                              void* d_out, int out_size, void* d_ws, size_t ws_size,
                              hipStream_t stream) {
    const int*   seq_s = (const int*)d_in[0];
    const int*   seq_o = (const int*)d_in[1];
    const int*   seq_r = (const int*)d_in[2];
    const float* seq_t = (const float*)d_in[3];
    const float* mem0  = (const float*)d_in[4];
    const float* lt0   = (const float*)d_in[5];
    const float* rel   = (const float*)d_in[6];
    const float* W_hidden = (const float*)d_in[7];
    const float* W_hh  = (const float*)d_in[8];
    const float* W_st  = (const float*)d_in[9];
    const float* W_ot  = (const float*)d_in[10];
    const float* Wq    = (const float*)d_in[11];
    const float* Wk    = (const float*)d_in[12];
    const float* Wv    = (const float*)d_in[13];
    const float* Wo    = (const float*)d_in[14];
    const float* sW1   = (const float*)d_in[15];
    const float* sb1   = (const float*)d_in[16];
    const float* sW2   = (const float*)d_in[17];
    const float* sb2   = (const float*)d_in[18];

    float* out      = (float*)d_out;
    float* out_lam  = out + 1;
    float* out_mem  = out + 2049;
    float* out_lt   = out + 2049 + (size_t)NE * DD;

    float* ws = (float*)d_ws;
    float* evt   = ws;                         // 655360
    float* xbuf  = ws + 655360;                // 655360
    float* ebuf  = ws + 1310720;               // 919552
    float* tebuf = ws + 2230272;               // 262144
    float* qbuf  = ws + 2492416;               // 655360
    float* kbuf  = ws + 3147776;               // 655360
    float* vbuf  = ws + 3803136;               // 655360
    float* aobuf = ws + 4458496;               // 655360
    float* slotDt   = ws + 5113856;            // 4096
    int*   slotPrev = (int*)(ws + 5117952);    // 4096
    int*   slotWin  = (int*)(ws + 5122048);    // 4096
    int*   fixList  = (int*)(ws + 5126144);    // 2048
    int*   fixState = (int*)(ws + 5128192);    // 2048
    int*   evFixIdx = (int*)(ws + 5130240);    // 2048
    int*   fixCnt   = (int*)(ws + 5132288);    // 1

    // Outputs: start from initial state (touched entities overwritten by scatter_win).
    hipMemcpyAsync(out_mem, mem0, (size_t)NE * DD * sizeof(float), hipMemcpyDeviceToDevice, stream);
    hipMemcpyAsync(out_lt,  lt0,  (size_t)NE * sizeof(float),      hipMemcpyDeviceToDevice, stream);
    hipMemsetAsync(fixCnt, 0, sizeof(int), stream);
    hipMemsetAsync(out, 0, sizeof(float), stream);     // loss accumulator

    slot_analyze<<<NSLOT / 4, 256, 0, stream>>>(seq_s, seq_o, seq_t, lt0,
                                                slotDt, slotPrev, slotWin);
    fixlist_build<<<NEV / 256, 256, 0, stream>>>(slotPrev, fixList, fixState,
                                                 evFixIdx, fixCnt);
    event_compute<<<NEV / 8, 256, 0, stream>>>(seq_s, seq_o, seq_r, seq_t, mem0, rel,
                                               W_hidden, W_hh, W_st, W_ot, slotDt,
                                               evt, ebuf, tebuf);
    for (int r = 0; r < 4; ++r)
        fix_round<<<64, 256, 0, stream>>>(r, seq_s, seq_o, mem0, W_hidden, W_hh,
                                          W_st, W_ot, slotDt, slotPrev,
                                          fixList, fixState, evFixIdx, fixCnt, evt, ebuf);
    scatter_win<<<512, 256, 0, stream>>>(seq_s, seq_o, seq_t, slotWin, evt, out_mem, out_lt);

    for (int l = 0; l < 2; ++l) {
        const float* src = l ? xbuf : evt;     // residual input
        proj<<<dim3(32, 5, 3), 256, 0, stream>>>(ebuf,
                                                 Wq + (size_t)l * IND * FEAT,
                                                 Wk + (size_t)l * IND * FEAT,
                                                 Wv + (size_t)l * IND * FEAT,
                                                 qbuf, kbuf, vbuf);
        attn<<<128, 256, 0, stream>>>(qbuf, kbuf, vbuf, aobuf);
        outproj<<<dim3(32, 5), 256, 0, stream>>>(aobuf, Wo + (size_t)l * FEAT * FEAT,
                                                 src, xbuf, ebuf, (l == 0) ? 1 : 0);
    }
    score_k<<<NEV, 128, 0, stream>>>(xbuf, sW1, sb1, sW2, sb2, out_lam, out);
}

// Round 3
// 625.301 us; speedup vs baseline: 1.2474x; 1.2474x over previous
//
#include <hip/hip_runtime.h>

// ---------------- problem dims ----------------
#define NE   200000
#define DC   64
#define DL   256
#define DD   128
#define FEAT 320          // 2*DD + DC
#define IND  449          // FEAT + DD + 1
#define INDP 480          // ebuf padded row stride (449 -> 480, pad zero-filled)
#define DH   80
#define BB   32
#define TT   64
#define NEV  2048         // BB*TT
#define NSLOT 4096

typedef __attribute__((ext_vector_type(4))) float  floatx4;

__device__ __forceinline__ float sigmoidf_(float x) { return 1.0f / (1.0f + __expf(-x)); }

// ---------------- K1: slot analysis (prev-toucher, dt, winner) ----------------
__global__ __launch_bounds__(256)
void slot_analyze(const int* __restrict__ seq_s, const int* __restrict__ seq_o,
                  const float* __restrict__ seq_time, const float* __restrict__ lt0,
                  float* __restrict__ slotDt, int* __restrict__ slotPrev,
                  int* __restrict__ slotWin) {
    __shared__ int entL[NSLOT];
    int tid = threadIdx.x;
    for (int j = tid; j < NSLOT; j += 256) {
        int b = j & 31, side = (j >> 5) & 1, t = j >> 6;
        entL[j] = (side ? seq_o : seq_s)[b * TT + t];
    }
    __syncthreads();
    int wave = tid >> 6, lane = tid & 63;
    int slot = blockIdx.x * 4 + wave;
    int t = slot >> 6;
    int myent = entL[slot];
    int win = 1, best = -1;
#pragma unroll 8
    for (int jj = 0; jj < NSLOT / 64; ++jj) {
        int j = jj * 64 + lane;
        if (entL[j] == myent) {
            if (j > slot) win = 0;
            else if ((j >> 6) < t && j > best) best = j;   // keeps max key among prior steps
        }
    }
#pragma unroll
    for (int off = 32; off; off >>= 1) {
        int ob = __shfl_xor(best, off, 64);
        best = best > ob ? best : ob;
    }
    win = __all(win);
    if (lane == 0) {
        int b = slot & 31;
        float tv = seq_time[b * TT + t];
        float pt = (best >= 0) ? seq_time[(best & 31) * TT + (best >> 6)] : lt0[myent];
        slotDt[slot]   = tv - pt;
        slotPrev[slot] = best;
        slotWin[slot]  = win;
    }
}

// ---------------- K1b: build fix list ----------------
__global__ __launch_bounds__(256)
void fixlist_build(const int* __restrict__ slotPrev, int* __restrict__ fixList,
                   int* __restrict__ fixState, int* __restrict__ evFixIdx,
                   int* __restrict__ fixCnt) {
    int e = blockIdx.x * 256 + threadIdx.x;   // 2048 events
    int b = e >> 6, t = e & 63;
    int c = (slotPrev[t * 64 + b] >= 0) | (slotPrev[t * 64 + 32 + b] >= 0);
    int idx = -1;
    if (c) { idx = atomicAdd(fixCnt, 1); fixList[idx] = e; fixState[idx] = -1; }
    evFixIdx[e] = idx;
}

// ---------------- K2: all-events parallel RNN compute (fp32) ----------------
__global__ __launch_bounds__(256)
void event_compute(const int* __restrict__ seq_s, const int* __restrict__ seq_o,
                   const int* __restrict__ seq_r, const float* __restrict__ seq_time,
                   const float* __restrict__ mem0, const float* __restrict__ rel,
                   const float* __restrict__ W_hidden, const float* __restrict__ W_hh,
                   const float* __restrict__ W_st, const float* __restrict__ W_ot,
                   const float* __restrict__ slotDt,
                   float* __restrict__ evt, float* __restrict__ ebuf) {
    __shared__ float xc[8][FEAT];
    __shared__ float hs[8][DL];
    __shared__ int   sSi[8], sOi[8], sRi[8];
    __shared__ float sDs[8], sDo[8], sTv[8];
    int tid = threadIdx.x;
    int e0 = blockIdx.x * 8;
    if (tid < 8) {
        int e = e0 + tid;
        sSi[tid] = seq_s[e]; sOi[tid] = seq_o[e]; sRi[tid] = seq_r[e];
        int b = e >> 6, t = e & 63;
        sDs[tid] = slotDt[t * 64 + b];
        sDo[tid] = slotDt[t * 64 + 32 + b];
        sTv[tid] = seq_time[e];
    }
    __syncthreads();
    for (int i = tid; i < 8 * FEAT; i += 256) {
        int r = i / FEAT, k = i - r * FEAT;
        float v;
        if (k < DD)            v = mem0[(size_t)sSi[r] * DD + k];
        else if (k < 2 * DD)   v = mem0[(size_t)sOi[r] * DD + (k - DD)];
        else                   v = rel[(size_t)sRi[r] * DC + (k - 2 * DD)];
        xc[r][k] = v;
    }
    __syncthreads();
    {   // z = xc @ W_hidden ; h = sigmoid(z)
        int j = tid;
        float acc[8] = {0.f,0.f,0.f,0.f,0.f,0.f,0.f,0.f};
        for (int k = 0; k < FEAT; ++k) {
            float w = W_hidden[(size_t)k * DL + j];
#pragma unroll
            for (int r = 0; r < 8; ++r) acc[r] += xc[r][k] * w;
        }
#pragma unroll
        for (int r = 0; r < 8; ++r) hs[r][j] = sigmoidf_(acc[r]);
    }
    __syncthreads();
    {   // hh = h @ W_hh ; ns/no = sigmoid(dt*W + hh)
        int d = tid & 127, grp = tid >> 7;
        float acc[4] = {0.f,0.f,0.f,0.f};
        for (int l = 0; l < DL; ++l) {
            float w = W_hh[(size_t)l * DD + d];
#pragma unroll
            for (int rr = 0; rr < 4; ++rr) acc[rr] += hs[grp * 4 + rr][l] * w;
        }
        float wst = W_st[d], wot = W_ot[d];
#pragma unroll
        for (int rr = 0; rr < 4; ++rr) {
            int r = grp * 4 + rr;
            int e = e0 + r;
            float ns  = sigmoidf_(sDs[r] * wst + acc[rr]);
            float no_ = sigmoidf_(sDo[r] * wot + acc[rr]);
            evt[(size_t)e * FEAT + d]      = ns;
            evt[(size_t)e * FEAT + DD + d] = no_;
            ebuf[(size_t)e * INDP + d]      = ns;
            ebuf[(size_t)e * INDP + DD + d] = no_;
        }
    }
    for (int i = tid; i < 8 * DC; i += 256) {
        int r = i >> 6, c = i & 63;
        float v = xc[r][2 * DD + c];
        int e = e0 + r;
        evt[(size_t)e * FEAT + 2 * DD + c] = v;
        ebuf[(size_t)e * INDP + 2 * DD + c] = v;
    }
    for (int i = tid; i < 8 * DD; i += 256) {
        int r = i >> 7, d = i & 127;
        float denom = __powf(1.0e4f, (float)d);     // inf for d>=10 -> 1/inf = 0 (matches ref)
        float v = sinf(sTv[r] * (1.0f / denom));
        int e = e0 + r;
        ebuf[(size_t)e * INDP + FEAT + d] = v;
    }
    if (tid < 8) ebuf[(size_t)(e0 + tid) * INDP + FEAT + DD] = 1.0f;
}

// ---------------- K3: fix rounds ----------------
__global__ __launch_bounds__(256)
void fix_round(int round,
               const int* __restrict__ seq_s, const int* __restrict__ seq_o,
               const float* __restrict__ mem0, const float* __restrict__ W_hidden,
               const float* __restrict__ W_hh, const float* __restrict__ W_st,
               const float* __restrict__ W_ot, const float* __restrict__ slotDt,
               const int* __restrict__ slotPrev, const int* __restrict__ fixList,
               int* __restrict__ fixState, const int* __restrict__ evFixIdx,
               const int* __restrict__ fixCnt,
               float* __restrict__ evt, float* __restrict__ ebuf) {
    __shared__ float xc[FEAT];
    __shared__ float hsv[DL];
    __shared__ float hp[2][DD];
    __shared__ int sGo, sPs, sPo, sE;
    int tid = threadIdx.x;
    int n = *fixCnt;
    for (int f = blockIdx.x; f < n; f += gridDim.x) {
        if (tid == 0) {
            int go = 0, ps = 0, po = 0, e = 0;
            if (fixState[f] == -1) {
                e = fixList[f];
                int b = e >> 6, t = e & 63;
                ps = slotPrev[t * 64 + b];
                po = slotPrev[t * 64 + 32 + b];
                go = 1;
                if (ps >= 0) {
                    int pe = (ps & 31) * 64 + (ps >> 6);
                    int fi = evFixIdx[pe];
                    if (fi >= 0) { int st = fixState[fi]; if (st < 0 || st >= round) go = 0; }
                }
                if (po >= 0) {
                    int pe = (po & 31) * 64 + (po >> 6);
                    int fi = evFixIdx[pe];
                    if (fi >= 0) { int st = fixState[fi]; if (st < 0 || st >= round) go = 0; }
                }
            }
            sGo = go; sPs = ps; sPo = po; sE = e;
        }
        __syncthreads();
        int go = sGo, ps = sPs, po = sPo, e = sE;
        __syncthreads();
        if (!go) continue;
        int b = e >> 6, t = e & 63;
        for (int i = tid; i < FEAT; i += 256) {
            float v;
            if (i < DD) {
                v = (ps >= 0) ? evt[(size_t)((ps & 31) * 64 + (ps >> 6)) * FEAT + ((ps >> 5) & 1) * DD + i]
                              : mem0[(size_t)seq_s[e] * DD + i];
            } else if (i < 2 * DD) {
                int k = i - DD;
                v = (po >= 0) ? evt[(size_t)((po & 31) * 64 + (po >> 6)) * FEAT + ((po >> 5) & 1) * DD + k]
                              : mem0[(size_t)seq_o[e] * DD + k];
            } else {
                v = evt[(size_t)e * FEAT + i];
            }
            xc[i] = v;
        }
        __syncthreads();
        {
            float a0 = 0.f, a1 = 0.f, a2 = 0.f, a3 = 0.f;
            for (int k = 0; k < FEAT; k += 4) {
                a0 += xc[k]     * W_hidden[(size_t)k * DL + tid];
                a1 += xc[k + 1] * W_hidden[(size_t)(k + 1) * DL + tid];
                a2 += xc[k + 2] * W_hidden[(size_t)(k + 2) * DL + tid];
                a3 += xc[k + 3] * W_hidden[(size_t)(k + 3) * DL + tid];
            }
            hsv[tid] = sigmoidf_((a0 + a1) + (a2 + a3));
        }
        __syncthreads();
        {
            int d = tid & 127, g = tid >> 7;
            float a0 = 0.f, a1 = 0.f;
            int l0 = g * 128;
            for (int l = 0; l < 128; l += 2) {
                a0 += hsv[l0 + l]     * W_hh[(size_t)(l0 + l) * DD + d];
                a1 += hsv[l0 + l + 1] * W_hh[(size_t)(l0 + l + 1) * DD + d];
            }
            hp[g][d] = a0 + a1;
        }
        __syncthreads();
        if (tid < DD) {
            float hh = hp[0][tid] + hp[1][tid];
            float ns  = sigmoidf_(slotDt[t * 64 + b]      * W_st[tid] + hh);
            float no_ = sigmoidf_(slotDt[t * 64 + 32 + b] * W_ot[tid] + hh);
            evt[(size_t)e * FEAT + tid]      = ns;
            evt[(size_t)e * FEAT + DD + tid] = no_;
            ebuf[(size_t)e * INDP + tid]      = ns;
            ebuf[(size_t)e * INDP + DD + tid] = no_;
        }
        __syncthreads();
        __threadfence();
        if (tid == 0) fixState[f] = round;
        __syncthreads();
    }
}

// ---------------- K4: winner scatter to out_mem / out_lt ----------------
__global__ __launch_bounds__(256)
void scatter_win(const int* __restrict__ seq_s, const int* __restrict__ seq_o,
                 const float* __restrict__ seq_time, const int* __restrict__ slotWin,
                 const float* __restrict__ evt, float* __restrict__ out_mem,
                 float* __restrict__ out_lt) {
    int gid = blockIdx.x * 256 + threadIdx.x;   // 131072 = 4096 slots * 32
    int slot = gid >> 5, c = gid & 31;
    if (!slotWin[slot]) return;
    int b = slot & 31, side = (slot >> 5) & 1, t = slot >> 6;
    int e = b * TT + t;
    int ent = (side ? seq_o : seq_s)[e];
    floatx4 v = *(const floatx4*)&evt[(size_t)e * FEAT + side * DD + c * 4];
    *(floatx4*)&out_mem[(size_t)ent * DD + c * 4] = v;
    if (c == 0) out_lt[ent] = seq_time[e];
}

// ---------------- phase 2: latency-optimized GEMMs ----------------
// proj: C[2048][320] = A[2048][INDP] @ W[449][320] for z in {q,k,v}.
// 1 wave per block, 32x32 tile, BK=32, register double-buffer prefetch,
// transposed-A LDS so the inner k-step is 2x ds_read_b128 + 16 FMA.
__global__ __launch_bounds__(64)
void proj(const float* __restrict__ ebuf, const float* __restrict__ Wq,
          const float* __restrict__ Wk, const float* __restrict__ Wv,
          float* __restrict__ q, float* __restrict__ k, float* __restrict__ v) {
    __shared__ float AsT[32][33];   // [kk][r]
    __shared__ float Bs[32][36];    // [kk][c]
    const float* W = (blockIdx.z == 0) ? Wq : (blockIdx.z == 1) ? Wk : Wv;
    float* out = (blockIdx.z == 0) ? q : (blockIdx.z == 1) ? k : v;
    int lane = threadIdx.x;
    int row0 = blockIdx.x * 32, col0 = blockIdx.y * 32;
    int tx = lane & 7, ty = lane >> 3;
    const int sr = lane >> 3, sk4 = (lane & 7) * 4;
    floatx4 aR[4], bR[4], acc[4];
#pragma unroll
    for (int i = 0; i < 4; ++i) acc[i] = (floatx4){0.f, 0.f, 0.f, 0.f};
    const int NIT = (IND + 31) / 32;   // 15 (K padded to 480; pad cols of ebuf are zero)
    // prologue: prefetch tile 0
#pragma unroll
    for (int m = 0; m < 4; ++m) {
        int r = m * 8 + sr;
        aR[m] = *(const floatx4*)&ebuf[(size_t)(row0 + r) * INDP + sk4];
        bR[m] = (r < IND) ? *(const floatx4*)&W[(size_t)r * FEAT + col0 + sk4]
                          : (floatx4){0.f, 0.f, 0.f, 0.f};
    }
    for (int it = 0; it < NIT; ++it) {
        __syncthreads();
#pragma unroll
        for (int m = 0; m < 4; ++m) {
            int r = m * 8 + sr;
            AsT[sk4 + 0][r] = aR[m][0];
            AsT[sk4 + 1][r] = aR[m][1];
            AsT[sk4 + 2][r] = aR[m][2];
            AsT[sk4 + 3][r] = aR[m][3];
            *(floatx4*)&Bs[r][sk4] = bR[m];
        }
        __syncthreads();
        if (it + 1 < NIT) {                      // prefetch next tile (overlaps compute)
            int k0n = (it + 1) * 32;
#pragma unroll
            for (int m = 0; m < 4; ++m) {
                int r = m * 8 + sr;
                aR[m] = *(const floatx4*)&ebuf[(size_t)(row0 + r) * INDP + k0n + sk4];
                int kg = k0n + r;
                bR[m] = (kg < IND) ? *(const floatx4*)&W[(size_t)kg * FEAT + col0 + sk4]
                                   : (floatx4){0.f, 0.f, 0.f, 0.f};
            }
        }
#pragma unroll
        for (int kk = 0; kk < 32; ++kk) {
            floatx4 a = *(const floatx4*)&AsT[kk][ty * 4];
            floatx4 b = *(const floatx4*)&Bs[kk][tx * 4];
#pragma unroll
            for (int i = 0; i < 4; ++i) acc[i] += a[i] * b;
        }
    }
#pragma unroll
    for (int i = 0; i < 4; ++i)
        *(floatx4*)&out[(size_t)(row0 + ty * 4 + i) * FEAT + col0 + tx * 4] = acc[i];
}

// outproj: acc = A[2048][320] @ Wo[320][320]; x = resid + tanh(acc); optional ebuf write.
__global__ __launch_bounds__(64)
void outproj(const float* __restrict__ ain, const float* __restrict__ Wo,
             const float* __restrict__ resid, float* __restrict__ xout,
             float* __restrict__ ebufW, int writeE) {
    __shared__ float AsT[32][33];
    __shared__ float Bs[32][36];
    int lane = threadIdx.x;
    int row0 = blockIdx.x * 32, col0 = blockIdx.y * 32;
    int tx = lane & 7, ty = lane >> 3;
    const int sr = lane >> 3, sk4 = (lane & 7) * 4;
    floatx4 aR[4], bR[4], acc[4];
#pragma unroll
    for (int i = 0; i < 4; ++i) acc[i] = (floatx4){0.f, 0.f, 0.f, 0.f};
    const int NIT = FEAT / 32;   // 10, exact
#pragma unroll
    for (int m = 0; m < 4; ++m) {
        int r = m * 8 + sr;
        aR[m] = *(const floatx4*)&ain[(size_t)(row0 + r) * FEAT + sk4];
        bR[m] = *(const floatx4*)&Wo[(size_t)r * FEAT + col0 + sk4];
    }
    for (int it = 0; it < NIT; ++it) {
        __syncthreads();
#pragma unroll
        for (int m = 0; m < 4; ++m) {
            int r = m * 8 + sr;
            AsT[sk4 + 0][r] = aR[m][0];
            AsT[sk4 + 1][r] = aR[m][1];
            AsT[sk4 + 2][r] = aR[m][2];
            AsT[sk4 + 3][r] = aR[m][3];
            *(floatx4*)&Bs[r][sk4] = bR[m];
        }
        __syncthreads();
        if (it + 1 < NIT) {
            int k0n = (it + 1) * 32;
#pragma unroll
            for (int m = 0; m < 4; ++m) {
                int r = m * 8 + sr;
                aR[m] = *(const floatx4*)&ain[(size_t)(row0 + r) * FEAT + k0n + sk4];
                bR[m] = *(const floatx4*)&Wo[(size_t)(k0n + r) * FEAT + col0 + sk4];
            }
        }
#pragma unroll
        for (int kk = 0; kk < 32; ++kk) {
            floatx4 a = *(const floatx4*)&AsT[kk][ty * 4];
            floatx4 b = *(const floatx4*)&Bs[kk][tx * 4];
#pragma unroll
            for (int i = 0; i < 4; ++i) acc[i] += a[i] * b;
        }
    }
#pragma unroll
    for (int i = 0; i < 4; ++i) {
        int row = row0 + ty * 4 + i;
        int c0 = col0 + tx * 4;
        floatx4 res = *(const floatx4*)&resid[(size_t)row * FEAT + c0];
        floatx4 o;
#pragma unroll
        for (int j = 0; j < 4; ++j) o[j] = res[j] + tanhf(acc[i][j]);
        *(floatx4*)&xout[(size_t)row * FEAT + c0] = o;
        if (writeE) *(floatx4*)&ebufW[(size_t)row * INDP + c0] = o;
    }
}

__global__ __launch_bounds__(256)
void attn(const float* __restrict__ q, const float* __restrict__ k,
          const float* __restrict__ v, float* __restrict__ ao) {
    __shared__ float qs[TT][DH], ks[TT][DH], vs[TT][DH];
    __shared__ float sc[TT][TT + 1];
    int bh = blockIdx.x;
    int b = bh >> 2, h = bh & 3;
    int tid = threadIdx.x;
    for (int i = tid; i < TT * DH; i += 256) {
        int r = i / DH, d = i - r * DH;
        size_t base = (size_t)(b * TT + r) * FEAT + h * DH + d;
        qs[r][d] = q[base]; ks[r][d] = k[base]; vs[r][d] = v[base];
    }
    __syncthreads();
    const float scale = 0.11180339887498949f;   // 1/sqrt(80)
    for (int idx = tid; idx < TT * TT; idx += 256) {
        int i = idx >> 6, j = idx & 63;
        float s = 0.f;
        for (int d = 0; d < DH; ++d) s += qs[i][d] * ks[j][d];
        sc[i][j] = s * scale;
    }
    __syncthreads();
    if (tid < TT) {
        int i = tid;
        if (i == 0) {
            for (int j = 0; j < TT; ++j) sc[0][j] = 0.0f;
        } else {
            float m = -1e30f;
            for (int j = 0; j < i; ++j) m = fmaxf(m, sc[i][j]);
            float sum = 0.f;
            for (int j = 0; j < i; ++j) { float p = __expf(sc[i][j] - m); sc[i][j] = p; sum += p; }
            float inv = 1.0f / sum;
            for (int j = 0; j < i; ++j) sc[i][j] *= inv;
            for (int j = i; j < TT; ++j) sc[i][j] = 0.0f;
        }
    }
    __syncthreads();
    for (int idx = tid; idx < TT * DH; idx += 256) {
        int i = idx / DH, d = idx - i * DH;
        float s = 0.f;
        for (int j = 0; j < TT; ++j) s += sc[i][j] * vs[j][d];
        ao[(size_t)(b * TT + i) * FEAT + h * DH + d] = s;
    }
}

__global__ __launch_bounds__(128)
void score_k(const float* __restrict__ x, const float* __restrict__ W1,
             const float* __restrict__ b1, const float* __restrict__ W2,
             const float* __restrict__ b2, float* __restrict__ lam_out,
             float* __restrict__ loss_out) {
    __shared__ float xr[FEAT];
    __shared__ float red[2];
    int e = blockIdx.x;
    int tid = threadIdx.x;
    for (int f = tid; f < FEAT; f += 128) xr[f] = x[(size_t)e * FEAT + f];
    __syncthreads();
    int d = tid;
    float acc = b1[d];
    for (int kk = 0; kk < FEAT; ++kk) acc += xr[kk] * W1[kk * DD + d];
    acc = fmaxf(acc, 0.0f) * W2[d];
    for (int off = 32; off; off >>= 1) acc += __shfl_down(acc, off, 64);
    if ((tid & 63) == 0) red[tid >> 6] = acc;
    __syncthreads();
    if (tid == 0) {
        float s = red[0] + red[1] + b2[0];
        float lam = fmaxf(s, 0.0f) + log1pf(expf(-fabsf(s)));   // softplus
        lam_out[e] = lam;
        atomicAdd(loss_out, -logf(lam + 1e-8f) * (1.0f / 2048.0f));
    }
}

// ---------------- launch ----------------
extern "C" void kernel_launch(void* const* d_in, const int* in_sizes, int n_in,
                              void* d_out, int out_size, void* d_ws, size_t ws_size,
                              hipStream_t stream) {
    const int*   seq_s = (const int*)d_in[0];
    const int*   seq_o = (const int*)d_in[1];
    const int*   seq_r = (const int*)d_in[2];
    const float* seq_t = (const float*)d_in[3];
    const float* mem0  = (const float*)d_in[4];
    const float* lt0   = (const float*)d_in[5];
    const float* rel   = (const float*)d_in[6];
    const float* W_hidden = (const float*)d_in[7];
    const float* W_hh  = (const float*)d_in[8];
    const float* W_st  = (const float*)d_in[9];
    const float* W_ot  = (const float*)d_in[10];
    const float* Wq    = (const float*)d_in[11];
    const float* Wk    = (const float*)d_in[12];
    const float* Wv    = (const float*)d_in[13];
    const float* Wo    = (const float*)d_in[14];
    const float* sW1   = (const float*)d_in[15];
    const float* sb1   = (const float*)d_in[16];
    const float* sW2   = (const float*)d_in[17];
    const float* sb2   = (const float*)d_in[18];

    float* out      = (float*)d_out;
    float* out_lam  = out + 1;
    float* out_mem  = out + 2049;
    float* out_lt   = out + 2049 + (size_t)NE * DD;

    float* ws = (float*)d_ws;
    float* evt   = ws;                         // 655360
    float* xbuf  = ws + 655360;                // 655360
    float* ebuf  = ws + 1310720;               // 2048*480 = 983040
    float* qbuf  = ws + 2293760;               // 655360
    float* kbuf  = ws + 2949120;               // 655360
    float* vbuf  = ws + 3604480;               // 655360
    float* aobuf = ws + 4259840;               // 655360
    float* slotDt   = ws + 4915200;            // 4096
    int*   slotPrev = (int*)(ws + 4919296);    // 4096
    int*   slotWin  = (int*)(ws + 4923392);    // 4096
    int*   fixList  = (int*)(ws + 4927488);    // 2048
    int*   fixState = (int*)(ws + 4929536);    // 2048
    int*   evFixIdx = (int*)(ws + 4931584);    // 2048
    int*   fixCnt   = (int*)(ws + 4933632);    // 1

    hipMemcpyAsync(out_mem, mem0, (size_t)NE * DD * sizeof(float), hipMemcpyDeviceToDevice, stream);
    hipMemcpyAsync(out_lt,  lt0,  (size_t)NE * sizeof(float),      hipMemcpyDeviceToDevice, stream);
    hipMemsetAsync(fixCnt, 0, sizeof(int), stream);
    hipMemsetAsync(out, 0, sizeof(float), stream);
    hipMemsetAsync(ebuf, 0, (size_t)NEV * INDP * sizeof(float), stream);   // zero K-pad cols

    slot_analyze<<<NSLOT / 4, 256, 0, stream>>>(seq_s, seq_o, seq_t, lt0,
                                                slotDt, slotPrev, slotWin);
    fixlist_build<<<NEV / 256, 256, 0, stream>>>(slotPrev, fixList, fixState,
                                                 evFixIdx, fixCnt);
    event_compute<<<NEV / 8, 256, 0, stream>>>(seq_s, seq_o, seq_r, seq_t, mem0, rel,
                                               W_hidden, W_hh, W_st, W_ot, slotDt,
                                               evt, ebuf);
    for (int r = 0; r < 4; ++r)
        fix_round<<<64, 256, 0, stream>>>(r, seq_s, seq_o, mem0, W_hidden, W_hh,
                                          W_st, W_ot, slotDt, slotPrev,
                                          fixList, fixState, evFixIdx, fixCnt, evt, ebuf);
    scatter_win<<<512, 256, 0, stream>>>(seq_s, seq_o, seq_t, slotWin, evt, out_mem, out_lt);

    for (int l = 0; l < 2; ++l) {
        const float* src = l ? xbuf : evt;     // residual input
        proj<<<dim3(64, 10, 3), 64, 0, stream>>>(ebuf,
                                                 Wq + (size_t)l * IND * FEAT,
                                                 Wk + (size_t)l * IND * FEAT,
                                                 Wv + (size_t)l * IND * FEAT,
                                                 qbuf, kbuf, vbuf);
        attn<<<128, 256, 0, stream>>>(qbuf, kbuf, vbuf, aobuf);
        outproj<<<dim3(64, 10), 64, 0, stream>>>(aobuf, Wo + (size_t)l * FEAT * FEAT,
                                                 src, xbuf, ebuf, (l == 0) ? 1 : 0);
    }
    score_k<<<NEV, 128, 0, stream>>>(xbuf, sW1, sb1, sW2, sb2, out_lam, out);
}

// Round 4
// 603.315 us; speedup vs baseline: 1.2929x; 1.0364x over previous
//
#include <hip/hip_runtime.h>

// ---------------- problem dims ----------------
#define NE   200000
#define DC   64
#define DL   256
#define DD   128
#define FEAT 320          // 2*DD + DC
#define IND  449          // FEAT + DD + 1
#define INDP 480          // ebuf padded row stride (449 -> 480, pad zero-filled)
#define DH   80
#define BB   32
#define TT   64
#define NEV  2048         // BB*TT
#define NSLOT 4096

typedef __attribute__((ext_vector_type(4))) float  floatx4;

__device__ __forceinline__ float sigmoidf_(float x) { return 1.0f / (1.0f + __expf(-x)); }

// ---------------- K0: output-state init copy (mem0 -> out_mem, lt0 -> out_lt) ----------
// Replaces rocclr copyBuffer (81us @ 1.9TB/s). Grid-stride float4, 8 blocks/CU.
__global__ __launch_bounds__(256)
void copy_init(const float* __restrict__ mem0, const float* __restrict__ lt0,
               float* __restrict__ out_mem, float* __restrict__ out_lt) {
    const size_t nm4 = (size_t)NE * DD / 4;     // 6,400,000 float4
    const size_t nl4 = NE / 4;                  // 50,000 float4
    size_t gid = (size_t)blockIdx.x * 256 + threadIdx.x;
    size_t stride = (size_t)gridDim.x * 256;
    const floatx4* __restrict__ sm = (const floatx4*)mem0;
    floatx4* __restrict__ dm = (floatx4*)out_mem;
    for (size_t i = gid; i < nm4; i += stride) dm[i] = sm[i];
    const floatx4* __restrict__ sl = (const floatx4*)lt0;
    floatx4* __restrict__ dl = (floatx4*)out_lt;
    for (size_t i = gid; i < nl4; i += stride) dl[i] = sl[i];
}

// ---------------- K1: slot analysis (prev-toucher, dt, winner) ----------------
__global__ __launch_bounds__(256)
void slot_analyze(const int* __restrict__ seq_s, const int* __restrict__ seq_o,
                  const float* __restrict__ seq_time, const float* __restrict__ lt0,
                  float* __restrict__ slotDt, int* __restrict__ slotPrev,
                  int* __restrict__ slotWin) {
    __shared__ int entL[NSLOT];
    int tid = threadIdx.x;
    for (int j = tid; j < NSLOT; j += 256) {
        int b = j & 31, side = (j >> 5) & 1, t = j >> 6;
        entL[j] = (side ? seq_o : seq_s)[b * TT + t];
    }
    __syncthreads();
    int wave = tid >> 6, lane = tid & 63;
    int slot = blockIdx.x * 4 + wave;
    int t = slot >> 6;
    int myent = entL[slot];
    int win = 1, best = -1;
#pragma unroll 8
    for (int jj = 0; jj < NSLOT / 64; ++jj) {
        int j = jj * 64 + lane;
        if (entL[j] == myent) {
            if (j > slot) win = 0;
            else if ((j >> 6) < t && j > best) best = j;   // keeps max key among prior steps
        }
    }
#pragma unroll
    for (int off = 32; off; off >>= 1) {
        int ob = __shfl_xor(best, off, 64);
        best = best > ob ? best : ob;
    }
    win = __all(win);
    if (lane == 0) {
        int b = slot & 31;
        float tv = seq_time[b * TT + t];
        float pt = (best >= 0) ? seq_time[(best & 31) * TT + (best >> 6)] : lt0[myent];
        slotDt[slot]   = tv - pt;
        slotPrev[slot] = best;
        slotWin[slot]  = win;
    }
}

// ---------------- K1b: build fix list ----------------
__global__ __launch_bounds__(256)
void fixlist_build(const int* __restrict__ slotPrev, int* __restrict__ fixList,
                   int* __restrict__ fixState, int* __restrict__ evFixIdx,
                   int* __restrict__ fixCnt) {
    int e = blockIdx.x * 256 + threadIdx.x;   // 2048 events
    int b = e >> 6, t = e & 63;
    int c = (slotPrev[t * 64 + b] >= 0) | (slotPrev[t * 64 + 32 + b] >= 0);
    int idx = -1;
    if (c) { idx = atomicAdd(fixCnt, 1); fixList[idx] = e; fixState[idx] = -1; }
    evFixIdx[e] = idx;
}

// ---------------- K2: all-events parallel RNN compute (fp32) ----------------
__global__ __launch_bounds__(256)
void event_compute(const int* __restrict__ seq_s, const int* __restrict__ seq_o,
                   const int* __restrict__ seq_r, const float* __restrict__ seq_time,
                   const float* __restrict__ mem0, const float* __restrict__ rel,
                   const float* __restrict__ W_hidden, const float* __restrict__ W_hh,
                   const float* __restrict__ W_st, const float* __restrict__ W_ot,
                   const float* __restrict__ slotDt,
                   float* __restrict__ evt, float* __restrict__ ebuf) {
    __shared__ float xc[8][FEAT];
    __shared__ float hs[8][DL];
    __shared__ int   sSi[8], sOi[8], sRi[8];
    __shared__ float sDs[8], sDo[8], sTv[8];
    int tid = threadIdx.x;
    int e0 = blockIdx.x * 8;
    if (tid < 8) {
        int e = e0 + tid;
        sSi[tid] = seq_s[e]; sOi[tid] = seq_o[e]; sRi[tid] = seq_r[e];
        int b = e >> 6, t = e & 63;
        sDs[tid] = slotDt[t * 64 + b];
        sDo[tid] = slotDt[t * 64 + 32 + b];
        sTv[tid] = seq_time[e];
    }
    __syncthreads();
    for (int i = tid; i < 8 * FEAT; i += 256) {
        int r = i / FEAT, k = i - r * FEAT;
        float v;
        if (k < DD)            v = mem0[(size_t)sSi[r] * DD + k];
        else if (k < 2 * DD)   v = mem0[(size_t)sOi[r] * DD + (k - DD)];
        else                   v = rel[(size_t)sRi[r] * DC + (k - 2 * DD)];
        xc[r][k] = v;
    }
    __syncthreads();
    {   // z = xc @ W_hidden ; h = sigmoid(z)
        int j = tid;
        float acc[8] = {0.f,0.f,0.f,0.f,0.f,0.f,0.f,0.f};
        for (int k = 0; k < FEAT; ++k) {
            float w = W_hidden[(size_t)k * DL + j];
#pragma unroll
            for (int r = 0; r < 8; ++r) acc[r] += xc[r][k] * w;
        }
#pragma unroll
        for (int r = 0; r < 8; ++r) hs[r][j] = sigmoidf_(acc[r]);
    }
    __syncthreads();
    {   // hh = h @ W_hh ; ns/no = sigmoid(dt*W + hh)
        int d = tid & 127, grp = tid >> 7;
        float acc[4] = {0.f,0.f,0.f,0.f};
        for (int l = 0; l < DL; ++l) {
            float w = W_hh[(size_t)l * DD + d];
#pragma unroll
            for (int rr = 0; rr < 4; ++rr) acc[rr] += hs[grp * 4 + rr][l] * w;
        }
        float wst = W_st[d], wot = W_ot[d];
#pragma unroll
        for (int rr = 0; rr < 4; ++rr) {
            int r = grp * 4 + rr;
            int e = e0 + r;
            float ns  = sigmoidf_(sDs[r] * wst + acc[rr]);
            float no_ = sigmoidf_(sDo[r] * wot + acc[rr]);
            evt[(size_t)e * FEAT + d]      = ns;
            evt[(size_t)e * FEAT + DD + d] = no_;
            ebuf[(size_t)e * INDP + d]      = ns;
            ebuf[(size_t)e * INDP + DD + d] = no_;
        }
    }
    for (int i = tid; i < 8 * DC; i += 256) {
        int r = i >> 6, c = i & 63;
        float v = xc[r][2 * DD + c];
        int e = e0 + r;
        evt[(size_t)e * FEAT + 2 * DD + c] = v;
        ebuf[(size_t)e * INDP + 2 * DD + c] = v;
    }
    for (int i = tid; i < 8 * DD; i += 256) {
        int r = i >> 7, d = i & 127;
        float denom = __powf(1.0e4f, (float)d);     // inf for d>=10 -> 1/inf = 0 (matches ref)
        float v = sinf(sTv[r] * (1.0f / denom));
        int e = e0 + r;
        ebuf[(size_t)e * INDP + FEAT + d] = v;
    }
    if (tid < 8) ebuf[(size_t)(e0 + tid) * INDP + FEAT + DD] = 1.0f;
}

// ---------------- K3: fix rounds ----------------
__global__ __launch_bounds__(256)
void fix_round(int round,
               const int* __restrict__ seq_s, const int* __restrict__ seq_o,
               const float* __restrict__ mem0, const float* __restrict__ W_hidden,
               const float* __restrict__ W_hh, const float* __restrict__ W_st,
               const float* __restrict__ W_ot, const float* __restrict__ slotDt,
               const int* __restrict__ slotPrev, const int* __restrict__ fixList,
               int* __restrict__ fixState, const int* __restrict__ evFixIdx,
               const int* __restrict__ fixCnt,
               float* __restrict__ evt, float* __restrict__ ebuf) {
    __shared__ float xc[FEAT];
    __shared__ float hsv[DL];
    __shared__ float hp[2][DD];
    __shared__ int sGo, sPs, sPo, sE;
    int tid = threadIdx.x;
    int n = *fixCnt;
    for (int f = blockIdx.x; f < n; f += gridDim.x) {
        if (tid == 0) {
            int go = 0, ps = 0, po = 0, e = 0;
            if (fixState[f] == -1) {
                e = fixList[f];
                int b = e >> 6, t = e & 63;
                ps = slotPrev[t * 64 + b];
                po = slotPrev[t * 64 + 32 + b];
                go = 1;
                if (ps >= 0) {
                    int pe = (ps & 31) * 64 + (ps >> 6);
                    int fi = evFixIdx[pe];
                    if (fi >= 0) { int st = fixState[fi]; if (st < 0 || st >= round) go = 0; }
                }
                if (po >= 0) {
                    int pe = (po & 31) * 64 + (po >> 6);
                    int fi = evFixIdx[pe];
                    if (fi >= 0) { int st = fixState[fi]; if (st < 0 || st >= round) go = 0; }
                }
            }
            sGo = go; sPs = ps; sPo = po; sE = e;
        }
        __syncthreads();
        int go = sGo, ps = sPs, po = sPo, e = sE;
        __syncthreads();
        if (!go) continue;
        int b = e >> 6, t = e & 63;
        for (int i = tid; i < FEAT; i += 256) {
            float v;
            if (i < DD) {
                v = (ps >= 0) ? evt[(size_t)((ps & 31) * 64 + (ps >> 6)) * FEAT + ((ps >> 5) & 1) * DD + i]
                              : mem0[(size_t)seq_s[e] * DD + i];
            } else if (i < 2 * DD) {
                int k = i - DD;
                v = (po >= 0) ? evt[(size_t)((po & 31) * 64 + (po >> 6)) * FEAT + ((po >> 5) & 1) * DD + k]
                              : mem0[(size_t)seq_o[e] * DD + k];
            } else {
                v = evt[(size_t)e * FEAT + i];
            }
            xc[i] = v;
        }
        __syncthreads();
        {
            float a0 = 0.f, a1 = 0.f, a2 = 0.f, a3 = 0.f;
            for (int k = 0; k < FEAT; k += 4) {
                a0 += xc[k]     * W_hidden[(size_t)k * DL + tid];
                a1 += xc[k + 1] * W_hidden[(size_t)(k + 1) * DL + tid];
                a2 += xc[k + 2] * W_hidden[(size_t)(k + 2) * DL + tid];
                a3 += xc[k + 3] * W_hidden[(size_t)(k + 3) * DL + tid];
            }
            hsv[tid] = sigmoidf_((a0 + a1) + (a2 + a3));
        }
        __syncthreads();
        {
            int d = tid & 127, g = tid >> 7;
            float a0 = 0.f, a1 = 0.f;
            int l0 = g * 128;
            for (int l = 0; l < 128; l += 2) {
                a0 += hsv[l0 + l]     * W_hh[(size_t)(l0 + l) * DD + d];
                a1 += hsv[l0 + l + 1] * W_hh[(size_t)(l0 + l + 1) * DD + d];
            }
            hp[g][d] = a0 + a1;
        }
        __syncthreads();
        if (tid < DD) {
            float hh = hp[0][tid] + hp[1][tid];
            float ns  = sigmoidf_(slotDt[t * 64 + b]      * W_st[tid] + hh);
            float no_ = sigmoidf_(slotDt[t * 64 + 32 + b] * W_ot[tid] + hh);
            evt[(size_t)e * FEAT + tid]      = ns;
            evt[(size_t)e * FEAT + DD + tid] = no_;
            ebuf[(size_t)e * INDP + tid]      = ns;
            ebuf[(size_t)e * INDP + DD + tid] = no_;
        }
        __syncthreads();
        __threadfence();
        if (tid == 0) fixState[f] = round;
        __syncthreads();
    }
}

// ---------------- K4: winner scatter to out_mem / out_lt ----------------
__global__ __launch_bounds__(256)
void scatter_win(const int* __restrict__ seq_s, const int* __restrict__ seq_o,
                 const float* __restrict__ seq_time, const int* __restrict__ slotWin,
                 const float* __restrict__ evt, float* __restrict__ out_mem,
                 float* __restrict__ out_lt) {
    int gid = blockIdx.x * 256 + threadIdx.x;   // 131072 = 4096 slots * 32
    int slot = gid >> 5, c = gid & 31;
    if (!slotWin[slot]) return;
    int b = slot & 31, side = (slot >> 5) & 1, t = slot >> 6;
    int e = b * TT + t;
    int ent = (side ? seq_o : seq_s)[e];
    floatx4 v = *(const floatx4*)&evt[(size_t)e * FEAT + side * DD + c * 4];
    *(floatx4*)&out_mem[(size_t)ent * DD + c * 4] = v;
    if (c == 0) out_lt[ent] = seq_time[e];
}

// ---------------- phase 2: latency-optimized GEMMs ----------------
// proj: C[2048][320] = A[2048][INDP] @ W[449][320] for z in {q,k,v}.
// 1 wave per block, 32x32 tile, BK=32, register double-buffer prefetch,
// transposed-A LDS so the inner k-step is 2x ds_read_b128 + 16 FMA.
__global__ __launch_bounds__(64)
void proj(const float* __restrict__ ebuf, const float* __restrict__ Wq,
          const float* __restrict__ Wk, const float* __restrict__ Wv,
          float* __restrict__ q, float* __restrict__ k, float* __restrict__ v) {
    __shared__ float AsT[32][33];   // [kk][r]
    __shared__ float Bs[32][36];    // [kk][c]
    const float* W = (blockIdx.z == 0) ? Wq : (blockIdx.z == 1) ? Wk : Wv;
    float* out = (blockIdx.z == 0) ? q : (blockIdx.z == 1) ? k : v;
    int lane = threadIdx.x;
    int row0 = blockIdx.x * 32, col0 = blockIdx.y * 32;
    int tx = lane & 7, ty = lane >> 3;
    const int sr = lane >> 3, sk4 = (lane & 7) * 4;
    floatx4 aR[4], bR[4], acc[4];
#pragma unroll
    for (int i = 0; i < 4; ++i) acc[i] = (floatx4){0.f, 0.f, 0.f, 0.f};
    const int NIT = (IND + 31) / 32;   // 15 (K padded to 480; pad cols of ebuf are zero)
#pragma unroll
    for (int m = 0; m < 4; ++m) {
        int r = m * 8 + sr;
        aR[m] = *(const floatx4*)&ebuf[(size_t)(row0 + r) * INDP + sk4];
        bR[m] = (r < IND) ? *(const floatx4*)&W[(size_t)r * FEAT + col0 + sk4]
                          : (floatx4){0.f, 0.f, 0.f, 0.f};
    }
    for (int it = 0; it < NIT; ++it) {
        __syncthreads();
#pragma unroll
        for (int m = 0; m < 4; ++m) {
            int r = m * 8 + sr;
            AsT[sk4 + 0][r] = aR[m][0];
            AsT[sk4 + 1][r] = aR[m][1];
            AsT[sk4 + 2][r] = aR[m][2];
            AsT[sk4 + 3][r] = aR[m][3];
            *(floatx4*)&Bs[r][sk4] = bR[m];
        }
        __syncthreads();
        if (it + 1 < NIT) {                      // prefetch next tile (overlaps compute)
            int k0n = (it + 1) * 32;
#pragma unroll
            for (int m = 0; m < 4; ++m) {
                int r = m * 8 + sr;
                aR[m] = *(const floatx4*)&ebuf[(size_t)(row0 + r) * INDP + k0n + sk4];
                int kg = k0n + r;
                bR[m] = (kg < IND) ? *(const floatx4*)&W[(size_t)kg * FEAT + col0 + sk4]
                                   : (floatx4){0.f, 0.f, 0.f, 0.f};
            }
        }
#pragma unroll
        for (int kk = 0; kk < 32; ++kk) {
            floatx4 a = *(const floatx4*)&AsT[kk][ty * 4];
            floatx4 b = *(const floatx4*)&Bs[kk][tx * 4];
#pragma unroll
            for (int i = 0; i < 4; ++i) acc[i] += a[i] * b;
        }
    }
#pragma unroll
    for (int i = 0; i < 4; ++i)
        *(floatx4*)&out[(size_t)(row0 + ty * 4 + i) * FEAT + col0 + tx * 4] = acc[i];
}

// outproj: acc = A[2048][320] @ Wo[320][320]; x = resid + tanh(acc); optional ebuf write.
__global__ __launch_bounds__(64)
void outproj(const float* __restrict__ ain, const float* __restrict__ Wo,
             const float* __restrict__ resid, float* __restrict__ xout,
             float* __restrict__ ebufW, int writeE) {
    __shared__ float AsT[32][33];
    __shared__ float Bs[32][36];
    int lane = threadIdx.x;
    int row0 = blockIdx.x * 32, col0 = blockIdx.y * 32;
    int tx = lane & 7, ty = lane >> 3;
    const int sr = lane >> 3, sk4 = (lane & 7) * 4;
    floatx4 aR[4], bR[4], acc[4];
#pragma unroll
    for (int i = 0; i < 4; ++i) acc[i] = (floatx4){0.f, 0.f, 0.f, 0.f};
    const int NIT = FEAT / 32;   // 10, exact
#pragma unroll
    for (int m = 0; m < 4; ++m) {
        int r = m * 8 + sr;
        aR[m] = *(const floatx4*)&ain[(size_t)(row0 + r) * FEAT + sk4];
        bR[m] = *(const floatx4*)&Wo[(size_t)r * FEAT + col0 + sk4];
    }
    for (int it = 0; it < NIT; ++it) {
        __syncthreads();
#pragma unroll
        for (int m = 0; m < 4; ++m) {
            int r = m * 8 + sr;
            AsT[sk4 + 0][r] = aR[m][0];
            AsT[sk4 + 1][r] = aR[m][1];
            AsT[sk4 + 2][r] = aR[m][2];
            AsT[sk4 + 3][r] = aR[m][3];
            *(floatx4*)&Bs[r][sk4] = bR[m];
        }
        __syncthreads();
        if (it + 1 < NIT) {
            int k0n = (it + 1) * 32;
#pragma unroll
            for (int m = 0; m < 4; ++m) {
                int r = m * 8 + sr;
                aR[m] = *(const floatx4*)&ain[(size_t)(row0 + r) * FEAT + k0n + sk4];
                bR[m] = *(const floatx4*)&Wo[(size_t)(k0n + r) * FEAT + col0 + sk4];
            }
        }
#pragma unroll
        for (int kk = 0; kk < 32; ++kk) {
            floatx4 a = *(const floatx4*)&AsT[kk][ty * 4];
            floatx4 b = *(const floatx4*)&Bs[kk][tx * 4];
#pragma unroll
            for (int i = 0; i < 4; ++i) acc[i] += a[i] * b;
        }
    }
#pragma unroll
    for (int i = 0; i < 4; ++i) {
        int row = row0 + ty * 4 + i;
        int c0 = col0 + tx * 4;
        floatx4 res = *(const floatx4*)&resid[(size_t)row * FEAT + c0];
        floatx4 o;
#pragma unroll
        for (int j = 0; j < 4; ++j) o[j] = res[j] + tanhf(acc[i][j]);
        *(floatx4*)&xout[(size_t)row * FEAT + c0] = o;
        if (writeE) *(floatx4*)&ebufW[(size_t)row * INDP + c0] = o;
    }
}

__global__ __launch_bounds__(256)
void attn(const float* __restrict__ q, const float* __restrict__ k,
          const float* __restrict__ v, float* __restrict__ ao) {
    __shared__ float qs[TT][DH], ks[TT][DH], vs[TT][DH];
    __shared__ float sc[TT][TT + 1];
    int bh = blockIdx.x;
    int b = bh >> 2, h = bh & 3;
    int tid = threadIdx.x;
    for (int i = tid; i < TT * DH; i += 256) {
        int r = i / DH, d = i - r * DH;
        size_t base = (size_t)(b * TT + r) * FEAT + h * DH + d;
        qs[r][d] = q[base]; ks[r][d] = k[base]; vs[r][d] = v[base];
    }
    __syncthreads();
    const float scale = 0.11180339887498949f;   // 1/sqrt(80)
    for (int idx = tid; idx < TT * TT; idx += 256) {
        int i = idx >> 6, j = idx & 63;
        float s = 0.f;
        for (int d = 0; d < DH; ++d) s += qs[i][d] * ks[j][d];
        sc[i][j] = s * scale;
    }
    __syncthreads();
    if (tid < TT) {
        int i = tid;
        if (i == 0) {
            for (int j = 0; j < TT; ++j) sc[0][j] = 0.0f;
        } else {
            float m = -1e30f;
            for (int j = 0; j < i; ++j) m = fmaxf(m, sc[i][j]);
            float sum = 0.f;
            for (int j = 0; j < i; ++j) { float p = __expf(sc[i][j] - m); sc[i][j] = p; sum += p; }
            float inv = 1.0f / sum;
            for (int j = 0; j < i; ++j) sc[i][j] *= inv;
            for (int j = i; j < TT; ++j) sc[i][j] = 0.0f;
        }
    }
    __syncthreads();
    for (int idx = tid; idx < TT * DH; idx += 256) {
        int i = idx / DH, d = idx - i * DH;
        float s = 0.f;
        for (int j = 0; j < TT; ++j) s += sc[i][j] * vs[j][d];
        ao[(size_t)(b * TT + i) * FEAT + h * DH + d] = s;
    }
}

__global__ __launch_bounds__(128)
void score_k(const float* __restrict__ x, const float* __restrict__ W1,
             const float* __restrict__ b1, const float* __restrict__ W2,
             const float* __restrict__ b2, float* __restrict__ lam_out,
             float* __restrict__ loss_out) {
    __shared__ float xr[FEAT];
    __shared__ float red[2];
    int e = blockIdx.x;
    int tid = threadIdx.x;
    for (int f = tid; f < FEAT; f += 128) xr[f] = x[(size_t)e * FEAT + f];
    __syncthreads();
    int d = tid;
    float acc = b1[d];
    for (int kk = 0; kk < FEAT; ++kk) acc += xr[kk] * W1[kk * DD + d];
    acc = fmaxf(acc, 0.0f) * W2[d];
    for (int off = 32; off; off >>= 1) acc += __shfl_down(acc, off, 64);
    if ((tid & 63) == 0) red[tid >> 6] = acc;
    __syncthreads();
    if (tid == 0) {
        float s = red[0] + red[1] + b2[0];
        float lam = fmaxf(s, 0.0f) + log1pf(expf(-fabsf(s)));   // softplus
        lam_out[e] = lam;
        atomicAdd(loss_out, -logf(lam + 1e-8f) * (1.0f / 2048.0f));
    }
}

// ---------------- launch ----------------
extern "C" void kernel_launch(void* const* d_in, const int* in_sizes, int n_in,
                              void* d_out, int out_size, void* d_ws, size_t ws_size,
                              hipStream_t stream) {
    const int*   seq_s = (const int*)d_in[0];
    const int*   seq_o = (const int*)d_in[1];
    const int*   seq_r = (const int*)d_in[2];
    const float* seq_t = (const float*)d_in[3];
    const float* mem0  = (const float*)d_in[4];
    const float* lt0   = (const float*)d_in[5];
    const float* rel   = (const float*)d_in[6];
    const float* W_hidden = (const float*)d_in[7];
    const float* W_hh  = (const float*)d_in[8];
    const float* W_st  = (const float*)d_in[9];
    const float* W_ot  = (const float*)d_in[10];
    const float* Wq    = (const float*)d_in[11];
    const float* Wk    = (const float*)d_in[12];
    const float* Wv    = (const float*)d_in[13];
    const float* Wo    = (const float*)d_in[14];
    const float* sW1   = (const float*)d_in[15];
    const float* sb1   = (const float*)d_in[16];
    const float* sW2   = (const float*)d_in[17];
    const float* sb2   = (const float*)d_in[18];

    float* out      = (float*)d_out;
    float* out_lam  = out + 1;
    float* out_mem  = out + 2049;
    float* out_lt   = out + 2049 + (size_t)NE * DD;

    float* ws = (float*)d_ws;
    float* evt   = ws;                         // 655360
    float* xbuf  = ws + 655360;                // 655360
    float* ebuf  = ws + 1310720;               // 2048*480 = 983040
    float* qbuf  = ws + 2293760;               // 655360
    float* kbuf  = ws + 2949120;               // 655360
    float* vbuf  = ws + 3604480;               // 655360
    float* aobuf = ws + 4259840;               // 655360
    float* slotDt   = ws + 4915200;            // 4096
    int*   slotPrev = (int*)(ws + 4919296);    // 4096
    int*   slotWin  = (int*)(ws + 4923392);    // 4096
    int*   fixList  = (int*)(ws + 4927488);    // 2048
    int*   fixState = (int*)(ws + 4929536);    // 2048
    int*   evFixIdx = (int*)(ws + 4931584);    // 2048
    int*   fixCnt   = (int*)(ws + 4933632);    // 1

    hipMemsetAsync(fixCnt, 0, sizeof(int), stream);
    hipMemsetAsync(out, 0, sizeof(float), stream);
    hipMemsetAsync(ebuf, 0, (size_t)NEV * INDP * sizeof(float), stream);   // zero K-pad cols

    copy_init<<<2048, 256, 0, stream>>>(mem0, lt0, out_mem, out_lt);

    slot_analyze<<<NSLOT / 4, 256, 0, stream>>>(seq_s, seq_o, seq_t, lt0,
                                                slotDt, slotPrev, slotWin);
    fixlist_build<<<NEV / 256, 256, 0, stream>>>(slotPrev, fixList, fixState,
                                                 evFixIdx, fixCnt);
    event_compute<<<NEV / 8, 256, 0, stream>>>(seq_s, seq_o, seq_r, seq_t, mem0, rel,
                                               W_hidden, W_hh, W_st, W_ot, slotDt,
                                               evt, ebuf);
    for (int r = 0; r < 4; ++r)
        fix_round<<<64, 256, 0, stream>>>(r, seq_s, seq_o, mem0, W_hidden, W_hh,
                                          W_st, W_ot, slotDt, slotPrev,
                                          fixList, fixState, evFixIdx, fixCnt, evt, ebuf);
    scatter_win<<<512, 256, 0, stream>>>(seq_s, seq_o, seq_t, slotWin, evt, out_mem, out_lt);

    for (int l = 0; l < 2; ++l) {
        const float* src = l ? xbuf : evt;     // residual input
        proj<<<dim3(64, 10, 3), 64, 0, stream>>>(ebuf,
                                                 Wq + (size_t)l * IND * FEAT,
                                                 Wk + (size_t)l * IND * FEAT,
                                                 Wv + (size_t)l * IND * FEAT,
                                                 qbuf, kbuf, vbuf);
        attn<<<128, 256, 0, stream>>>(qbuf, kbuf, vbuf, aobuf);
        outproj<<<dim3(64, 10), 64, 0, stream>>>(aobuf, Wo + (size_t)l * FEAT * FEAT,
                                                 src, xbuf, ebuf, (l == 0) ? 1 : 0);
    }
    score_k<<<NEV, 128, 0, stream>>>(xbuf, sW1, sb1, sW2, sb2, out_lam, out);
}

// Round 5
// 562.902 us; speedup vs baseline: 1.3857x; 1.0718x over previous
//
#include <hip/hip_runtime.h>

// ---------------- problem dims ----------------
#define NE   200000
#define DC   64
#define DL   256
#define DD   128
#define FEAT 320          // 2*DD + DC
#define IND  449          // FEAT + DD + 1
#define INDP 512          // ebuf padded row stride (449 -> 512, pad zero-filled)
#define DH   80
#define BB   32
#define TT   64
#define NEV  2048         // BB*TT
#define NSLOT 4096

typedef __attribute__((ext_vector_type(4))) float  floatx4;

__device__ __forceinline__ float sigmoidf_(float x) { return 1.0f / (1.0f + __expf(-x)); }

// ---------------- K0: output-state init copy (mem0 -> out_mem, lt0 -> out_lt) ----------
__global__ __launch_bounds__(256)
void copy_init(const float* __restrict__ mem0, const float* __restrict__ lt0,
               float* __restrict__ out_mem, float* __restrict__ out_lt) {
    const size_t nm4 = (size_t)NE * DD / 4;     // 6,400,000 float4
    const size_t nl4 = NE / 4;                  // 50,000 float4
    size_t gid = (size_t)blockIdx.x * 256 + threadIdx.x;
    size_t stride = (size_t)gridDim.x * 256;
    const floatx4* __restrict__ sm = (const floatx4*)mem0;
    floatx4* __restrict__ dm = (floatx4*)out_mem;
    for (size_t i = gid; i < nm4; i += stride) dm[i] = sm[i];
    const floatx4* __restrict__ sl = (const floatx4*)lt0;
    floatx4* __restrict__ dl = (floatx4*)out_lt;
    for (size_t i = gid; i < nl4; i += stride) dl[i] = sl[i];
}

// ---------------- K1: slot analysis (prev-toucher, dt, winner) ----------------
__global__ __launch_bounds__(256)
void slot_analyze(const int* __restrict__ seq_s, const int* __restrict__ seq_o,
                  const float* __restrict__ seq_time, const float* __restrict__ lt0,
                  float* __restrict__ slotDt, int* __restrict__ slotPrev,
                  int* __restrict__ slotWin) {
    __shared__ int entL[NSLOT];
    int tid = threadIdx.x;
    for (int j = tid; j < NSLOT; j += 256) {
        int b = j & 31, side = (j >> 5) & 1, t = j >> 6;
        entL[j] = (side ? seq_o : seq_s)[b * TT + t];
    }
    __syncthreads();
    int wave = tid >> 6, lane = tid & 63;
    int slot = blockIdx.x * 4 + wave;
    int t = slot >> 6;
    int myent = entL[slot];
    int win = 1, best = -1;
#pragma unroll 8
    for (int jj = 0; jj < NSLOT / 64; ++jj) {
        int j = jj * 64 + lane;
        if (entL[j] == myent) {
            if (j > slot) win = 0;
            else if ((j >> 6) < t && j > best) best = j;   // keeps max key among prior steps
        }
    }
#pragma unroll
    for (int off = 32; off; off >>= 1) {
        int ob = __shfl_xor(best, off, 64);
        best = best > ob ? best : ob;
    }
    win = __all(win);
    if (lane == 0) {
        int b = slot & 31;
        float tv = seq_time[b * TT + t];
        float pt = (best >= 0) ? seq_time[(best & 31) * TT + (best >> 6)] : lt0[myent];
        slotDt[slot]   = tv - pt;
        slotPrev[slot] = best;
        slotWin[slot]  = win;
    }
}

// ---------------- K1b: build fix list ----------------
__global__ __launch_bounds__(256)
void fixlist_build(const int* __restrict__ slotPrev, int* __restrict__ fixList,
                   int* __restrict__ fixState, int* __restrict__ evFixIdx,
                   int* __restrict__ fixCnt) {
    int e = blockIdx.x * 256 + threadIdx.x;   // 2048 events
    int b = e >> 6, t = e & 63;
    int c = (slotPrev[t * 64 + b] >= 0) | (slotPrev[t * 64 + 32 + b] >= 0);
    int idx = -1;
    if (c) { idx = atomicAdd(fixCnt, 1); fixList[idx] = e; fixState[idx] = -1; }
    evFixIdx[e] = idx;
}

// ---------------- K2: all-events parallel RNN compute (fp32) ----------------
__global__ __launch_bounds__(256)
void event_compute(const int* __restrict__ seq_s, const int* __restrict__ seq_o,
                   const int* __restrict__ seq_r, const float* __restrict__ seq_time,
                   const float* __restrict__ mem0, const float* __restrict__ rel,
                   const float* __restrict__ W_hidden, const float* __restrict__ W_hh,
                   const float* __restrict__ W_st, const float* __restrict__ W_ot,
                   const float* __restrict__ slotDt,
                   float* __restrict__ evt, float* __restrict__ ebuf) {
    __shared__ float xc[8][FEAT];
    __shared__ float hs[8][DL];
    __shared__ int   sSi[8], sOi[8], sRi[8];
    __shared__ float sDs[8], sDo[8], sTv[8];
    int tid = threadIdx.x;
    int e0 = blockIdx.x * 8;
    if (tid < 8) {
        int e = e0 + tid;
        sSi[tid] = seq_s[e]; sOi[tid] = seq_o[e]; sRi[tid] = seq_r[e];
        int b = e >> 6, t = e & 63;
        sDs[tid] = slotDt[t * 64 + b];
        sDo[tid] = slotDt[t * 64 + 32 + b];
        sTv[tid] = seq_time[e];
    }
    __syncthreads();
    for (int i = tid; i < 8 * FEAT; i += 256) {
        int r = i / FEAT, k = i - r * FEAT;
        float v;
        if (k < DD)            v = mem0[(size_t)sSi[r] * DD + k];
        else if (k < 2 * DD)   v = mem0[(size_t)sOi[r] * DD + (k - DD)];
        else                   v = rel[(size_t)sRi[r] * DC + (k - 2 * DD)];
        xc[r][k] = v;
    }
    __syncthreads();
    {   // z = xc @ W_hidden ; h = sigmoid(z)
        int j = tid;
        float acc[8] = {0.f,0.f,0.f,0.f,0.f,0.f,0.f,0.f};
        for (int k = 0; k < FEAT; ++k) {
            float w = W_hidden[(size_t)k * DL + j];
#pragma unroll
            for (int r = 0; r < 8; ++r) acc[r] += xc[r][k] * w;
        }
#pragma unroll
        for (int r = 0; r < 8; ++r) hs[r][j] = sigmoidf_(acc[r]);
    }
    __syncthreads();
    {   // hh = h @ W_hh ; ns/no = sigmoid(dt*W + hh)
        int d = tid & 127, grp = tid >> 7;
        float acc[4] = {0.f,0.f,0.f,0.f};
        for (int l = 0; l < DL; ++l) {
            float w = W_hh[(size_t)l * DD + d];
#pragma unroll
            for (int rr = 0; rr < 4; ++rr) acc[rr] += hs[grp * 4 + rr][l] * w;
        }
        float wst = W_st[d], wot = W_ot[d];
#pragma unroll
        for (int rr = 0; rr < 4; ++rr) {
            int r = grp * 4 + rr;
            int e = e0 + r;
            float ns  = sigmoidf_(sDs[r] * wst + acc[rr]);
            float no_ = sigmoidf_(sDo[r] * wot + acc[rr]);
            evt[(size_t)e * FEAT + d]      = ns;
            evt[(size_t)e * FEAT + DD + d] = no_;
            ebuf[(size_t)e * INDP + d]      = ns;
            ebuf[(size_t)e * INDP + DD + d] = no_;
        }
    }
    for (int i = tid; i < 8 * DC; i += 256) {
        int r = i >> 6, c = i & 63;
        float v = xc[r][2 * DD + c];
        int e = e0 + r;
        evt[(size_t)e * FEAT + 2 * DD + c] = v;
        ebuf[(size_t)e * INDP + 2 * DD + c] = v;
    }
    for (int i = tid; i < 8 * DD; i += 256) {
        int r = i >> 7, d = i & 127;
        float denom = __powf(1.0e4f, (float)d);     // inf for d>=10 -> 1/inf = 0 (matches ref)
        float v = sinf(sTv[r] * (1.0f / denom));
        int e = e0 + r;
        ebuf[(size_t)e * INDP + FEAT + d] = v;
    }
    if (tid < 8) ebuf[(size_t)(e0 + tid) * INDP + FEAT + DD] = 1.0f;
}

// ---------------- K3: fix rounds ----------------
__global__ __launch_bounds__(256)
void fix_round(int round,
               const int* __restrict__ seq_s, const int* __restrict__ seq_o,
               const float* __restrict__ mem0, const float* __restrict__ W_hidden,
               const float* __restrict__ W_hh, const float* __restrict__ W_st,
               const float* __restrict__ W_ot, const float* __restrict__ slotDt,
               const int* __restrict__ slotPrev, const int* __restrict__ fixList,
               int* __restrict__ fixState, const int* __restrict__ evFixIdx,
               const int* __restrict__ fixCnt,
               float* __restrict__ evt, float* __restrict__ ebuf) {
    __shared__ float xc[FEAT];
    __shared__ float hsv[DL];
    __shared__ float hp[2][DD];
    __shared__ int sGo, sPs, sPo, sE;
    int tid = threadIdx.x;
    int n = *fixCnt;
    for (int f = blockIdx.x; f < n; f += gridDim.x) {
        if (tid == 0) {
            int go = 0, ps = 0, po = 0, e = 0;
            if (fixState[f] == -1) {
                e = fixList[f];
                int b = e >> 6, t = e & 63;
                ps = slotPrev[t * 64 + b];
                po = slotPrev[t * 64 + 32 + b];
                go = 1;
                if (ps >= 0) {
                    int pe = (ps & 31) * 64 + (ps >> 6);
                    int fi = evFixIdx[pe];
                    if (fi >= 0) { int st = fixState[fi]; if (st < 0 || st >= round) go = 0; }
                }
                if (po >= 0) {
                    int pe = (po & 31) * 64 + (po >> 6);
                    int fi = evFixIdx[pe];
                    if (fi >= 0) { int st = fixState[fi]; if (st < 0 || st >= round) go = 0; }
                }
            }
            sGo = go; sPs = ps; sPo = po; sE = e;
        }
        __syncthreads();
        int go = sGo, ps = sPs, po = sPo, e = sE;
        __syncthreads();
        if (!go) continue;
        int b = e >> 6, t = e & 63;
        for (int i = tid; i < FEAT; i += 256) {
            float v;
            if (i < DD) {
                v = (ps >= 0) ? evt[(size_t)((ps & 31) * 64 + (ps >> 6)) * FEAT + ((ps >> 5) & 1) * DD + i]
                              : mem0[(size_t)seq_s[e] * DD + i];
            } else if (i < 2 * DD) {
                int k = i - DD;
                v = (po >= 0) ? evt[(size_t)((po & 31) * 64 + (po >> 6)) * FEAT + ((po >> 5) & 1) * DD + k]
                              : mem0[(size_t)seq_o[e] * DD + k];
            } else {
                v = evt[(size_t)e * FEAT + i];
            }
            xc[i] = v;
        }
        __syncthreads();
        {
            float a0 = 0.f, a1 = 0.f, a2 = 0.f, a3 = 0.f;
            for (int k = 0; k < FEAT; k += 4) {
                a0 += xc[k]     * W_hidden[(size_t)k * DL + tid];
                a1 += xc[k + 1] * W_hidden[(size_t)(k + 1) * DL + tid];
                a2 += xc[k + 2] * W_hidden[(size_t)(k + 2) * DL + tid];
                a3 += xc[k + 3] * W_hidden[(size_t)(k + 3) * DL + tid];
            }
            hsv[tid] = sigmoidf_((a0 + a1) + (a2 + a3));
        }
        __syncthreads();
        {
            int d = tid & 127, g = tid >> 7;
            float a0 = 0.f, a1 = 0.f;
            int l0 = g * 128;
            for (int l = 0; l < 128; l += 2) {
                a0 += hsv[l0 + l]     * W_hh[(size_t)(l0 + l) * DD + d];
                a1 += hsv[l0 + l + 1] * W_hh[(size_t)(l0 + l + 1) * DD + d];
            }
            hp[g][d] = a0 + a1;
        }
        __syncthreads();
        if (tid < DD) {
            float hh = hp[0][tid] + hp[1][tid];
            float ns  = sigmoidf_(slotDt[t * 64 + b]      * W_st[tid] + hh);
            float no_ = sigmoidf_(slotDt[t * 64 + 32 + b] * W_ot[tid] + hh);
            evt[(size_t)e * FEAT + tid]      = ns;
            evt[(size_t)e * FEAT + DD + tid] = no_;
            ebuf[(size_t)e * INDP + tid]      = ns;
            ebuf[(size_t)e * INDP + DD + tid] = no_;
        }
        __syncthreads();
        __threadfence();
        if (tid == 0) fixState[f] = round;
        __syncthreads();
    }
}

// ---------------- K4: winner scatter to out_mem / out_lt ----------------
__global__ __launch_bounds__(256)
void scatter_win(const int* __restrict__ seq_s, const int* __restrict__ seq_o,
                 const float* __restrict__ seq_time, const int* __restrict__ slotWin,
                 const float* __restrict__ evt, float* __restrict__ out_mem,
                 float* __restrict__ out_lt) {
    int gid = blockIdx.x * 256 + threadIdx.x;   // 131072 = 4096 slots * 32
    int slot = gid >> 5, c = gid & 31;
    if (!slotWin[slot]) return;
    int b = slot & 31, side = (slot >> 5) & 1, t = slot >> 6;
    int e = b * TT + t;
    int ent = (side ? seq_o : seq_s)[e];
    floatx4 v = *(const floatx4*)&evt[(size_t)e * FEAT + side * DD + c * 4];
    *(floatx4*)&out_mem[(size_t)ent * DD + c * 4] = v;
    if (c == 0) out_lt[ent] = seq_time[e];
}

// ---------------- phase 2: split-K latency-optimized GEMMs ----------------
// proj: C[2048][320] = A[2048][512(INDP)] @ W[449][320] for z in {q,k,v}.
// 2 waves per block; wave w accumulates K in [w*256, w*256+256) into private LDS
// staging (equal 8-iter loops keep barriers aligned), then wave1 parks its
// partial in LDS and wave0 adds + stores. 3840 waves total (~3.8/SIMD).
__global__ __launch_bounds__(128)
void proj(const float* __restrict__ ebuf, const float* __restrict__ Wq,
          const float* __restrict__ Wk, const float* __restrict__ Wv,
          float* __restrict__ q, float* __restrict__ k, float* __restrict__ v) {
    __shared__ float AsT[2][32][33];   // [wave][kk][r]
    __shared__ float Bs[2][32][36];    // [wave][kk][c]
    __shared__ float comb[32][36];
    const float* W = (blockIdx.z == 0) ? Wq : (blockIdx.z == 1) ? Wk : Wv;
    float* out = (blockIdx.z == 0) ? q : (blockIdx.z == 1) ? k : v;
    int tid = threadIdx.x;
    int w = tid >> 6, lane = tid & 63;
    int row0 = blockIdx.x * 32, col0 = blockIdx.y * 32;
    int tx = lane & 7, ty = lane >> 3;
    const int sr = lane >> 3, sk4 = (lane & 7) * 4;
    const int IT0 = w * 8, IT1 = IT0 + 8;       // 16 iters total (K=512 padded)
    floatx4 aR[4], bR[4], acc[4];
#pragma unroll
    for (int i = 0; i < 4; ++i) acc[i] = (floatx4){0.f, 0.f, 0.f, 0.f};
    // prologue: prefetch first tile of this wave's K range
#pragma unroll
    for (int m = 0; m < 4; ++m) {
        int r = m * 8 + sr;
        int kg = IT0 * 32 + r;
        aR[m] = *(const floatx4*)&ebuf[(size_t)(row0 + r) * INDP + IT0 * 32 + sk4];
        bR[m] = (kg < IND) ? *(const floatx4*)&W[(size_t)kg * FEAT + col0 + sk4]
                           : (floatx4){0.f, 0.f, 0.f, 0.f};
    }
    for (int it = IT0; it < IT1; ++it) {
        __syncthreads();
#pragma unroll
        for (int m = 0; m < 4; ++m) {
            int r = m * 8 + sr;
            AsT[w][sk4 + 0][r] = aR[m][0];
            AsT[w][sk4 + 1][r] = aR[m][1];
            AsT[w][sk4 + 2][r] = aR[m][2];
            AsT[w][sk4 + 3][r] = aR[m][3];
            *(floatx4*)&Bs[w][r][sk4] = bR[m];
        }
        __syncthreads();
        if (it + 1 < IT1) {                      // prefetch next tile (overlaps compute)
            int k0n = (it + 1) * 32;
#pragma unroll
            for (int m = 0; m < 4; ++m) {
                int r = m * 8 + sr;
                int kg = k0n + r;
                aR[m] = *(const floatx4*)&ebuf[(size_t)(row0 + r) * INDP + k0n + sk4];
                bR[m] = (kg < IND) ? *(const floatx4*)&W[(size_t)kg * FEAT + col0 + sk4]
                                   : (floatx4){0.f, 0.f, 0.f, 0.f};
            }
        }
#pragma unroll
        for (int kk = 0; kk < 32; ++kk) {
            floatx4 a = *(const floatx4*)&AsT[w][kk][ty * 4];
            floatx4 b = *(const floatx4*)&Bs[w][kk][tx * 4];
#pragma unroll
            for (int i = 0; i < 4; ++i) acc[i] += a[i] * b;
        }
    }
    // combine: wave1 parks partial, wave0 adds and stores
    if (w == 1) {
#pragma unroll
        for (int i = 0; i < 4; ++i)
            *(floatx4*)&comb[ty * 4 + i][tx * 4] = acc[i];
    }
    __syncthreads();
    if (w == 0) {
#pragma unroll
        for (int i = 0; i < 4; ++i) {
            floatx4 p = *(const floatx4*)&comb[ty * 4 + i][tx * 4];
            floatx4 s = acc[i] + p;
            *(floatx4*)&out[(size_t)(row0 + ty * 4 + i) * FEAT + col0 + tx * 4] = s;
        }
    }
}

// outproj: acc = A[2048][320] @ Wo[320][320]; x = resid + tanh(acc); optional ebuf write.
// Same split-K structure: wave w handles K in [w*160, w*160+160), 5 iters each.
__global__ __launch_bounds__(128)
void outproj(const float* __restrict__ ain, const float* __restrict__ Wo,
             const float* __restrict__ resid, float* __restrict__ xout,
             float* __restrict__ ebufW, int writeE) {
    __shared__ float AsT[2][32][33];
    __shared__ float Bs[2][32][36];
    __shared__ float comb[32][36];
    int tid = threadIdx.x;
    int w = tid >> 6, lane = tid & 63;
    int row0 = blockIdx.x * 32, col0 = blockIdx.y * 32;
    int tx = lane & 7, ty = lane >> 3;
    const int sr = lane >> 3, sk4 = (lane & 7) * 4;
    const int IT0 = w * 5, IT1 = IT0 + 5;       // 10 iters total (K=320 exact)
    floatx4 aR[4], bR[4], acc[4];
#pragma unroll
    for (int i = 0; i < 4; ++i) acc[i] = (floatx4){0.f, 0.f, 0.f, 0.f};
#pragma unroll
    for (int m = 0; m < 4; ++m) {
        int r = m * 8 + sr;
        aR[m] = *(const floatx4*)&ain[(size_t)(row0 + r) * FEAT + IT0 * 32 + sk4];
        bR[m] = *(const floatx4*)&Wo[(size_t)(IT0 * 32 + r) * FEAT + col0 + sk4];
    }
    for (int it = IT0; it < IT1; ++it) {
        __syncthreads();
#pragma unroll
        for (int m = 0; m < 4; ++m) {
            int r = m * 8 + sr;
            AsT[w][sk4 + 0][r] = aR[m][0];
            AsT[w][sk4 + 1][r] = aR[m][1];
            AsT[w][sk4 + 2][r] = aR[m][2];
            AsT[w][sk4 + 3][r] = aR[m][3];
            *(floatx4*)&Bs[w][r][sk4] = bR[m];
        }
        __syncthreads();
        if (it + 1 < IT1) {
            int k0n = (it + 1) * 32;
#pragma unroll
            for (int m = 0; m < 4; ++m) {
                int r = m * 8 + sr;
                aR[m] = *(const floatx4*)&ain[(size_t)(row0 + r) * FEAT + k0n + sk4];
                bR[m] = *(const floatx4*)&Wo[(size_t)(k0n + r) * FEAT + col0 + sk4];
            }
        }
#pragma unroll
        for (int kk = 0; kk < 32; ++kk) {
            floatx4 a = *(const floatx4*)&AsT[w][kk][ty * 4];
            floatx4 b = *(const floatx4*)&Bs[w][kk][tx * 4];
#pragma unroll
            for (int i = 0; i < 4; ++i) acc[i] += a[i] * b;
        }
    }
    if (w == 1) {
#pragma unroll
        for (int i = 0; i < 4; ++i)
            *(floatx4*)&comb[ty * 4 + i][tx * 4] = acc[i];
    }
    __syncthreads();
    if (w == 0) {
#pragma unroll
        for (int i = 0; i < 4; ++i) {
            int row = row0 + ty * 4 + i;
            int c0 = col0 + tx * 4;
            floatx4 p = *(const floatx4*)&comb[ty * 4 + i][tx * 4];
            floatx4 a = acc[i] + p;
            floatx4 res = *(const floatx4*)&resid[(size_t)row * FEAT + c0];
            floatx4 o;
#pragma unroll
            for (int j = 0; j < 4; ++j) o[j] = res[j] + tanhf(a[j]);
            *(floatx4*)&xout[(size_t)row * FEAT + c0] = o;
            if (writeE) *(floatx4*)&ebufW[(size_t)row * INDP + c0] = o;
        }
    }
}

__global__ __launch_bounds__(256)
void attn(const float* __restrict__ q, const float* __restrict__ k,
          const float* __restrict__ v, float* __restrict__ ao) {
    __shared__ float qs[TT][DH], ks[TT][DH], vs[TT][DH];
    __shared__ float sc[TT][TT + 1];
    int bh = blockIdx.x;
    int b = bh >> 2, h = bh & 3;
    int tid = threadIdx.x;
    for (int i = tid; i < TT * DH; i += 256) {
        int r = i / DH, d = i - r * DH;
        size_t base = (size_t)(b * TT + r) * FEAT + h * DH + d;
        qs[r][d] = q[base]; ks[r][d] = k[base]; vs[r][d] = v[base];
    }
    __syncthreads();
    const float scale = 0.11180339887498949f;   // 1/sqrt(80)
    for (int idx = tid; idx < TT * TT; idx += 256) {
        int i = idx >> 6, j = idx & 63;
        float s = 0.f;
        for (int d = 0; d < DH; ++d) s += qs[i][d] * ks[j][d];
        sc[i][j] = s * scale;
    }
    __syncthreads();
    if (tid < TT) {
        int i = tid;
        if (i == 0) {
            for (int j = 0; j < TT; ++j) sc[0][j] = 0.0f;
        } else {
            float m = -1e30f;
            for (int j = 0; j < i; ++j) m = fmaxf(m, sc[i][j]);
            float sum = 0.f;
            for (int j = 0; j < i; ++j) { float p = __expf(sc[i][j] - m); sc[i][j] = p; sum += p; }
            float inv = 1.0f / sum;
            for (int j = 0; j < i; ++j) sc[i][j] *= inv;
            for (int j = i; j < TT; ++j) sc[i][j] = 0.0f;
        }
    }
    __syncthreads();
    for (int idx = tid; idx < TT * DH; idx += 256) {
        int i = idx / DH, d = idx - i * DH;
        float s = 0.f;
        for (int j = 0; j < TT; ++j) s += sc[i][j] * vs[j][d];
        ao[(size_t)(b * TT + i) * FEAT + h * DH + d] = s;
    }
}

__global__ __launch_bounds__(128)
void score_k(const float* __restrict__ x, const float* __restrict__ W1,
             const float* __restrict__ b1, const float* __restrict__ W2,
             const float* __restrict__ b2, float* __restrict__ lam_out,
             float* __restrict__ loss_out) {
    __shared__ float xr[FEAT];
    __shared__ float red[2];
    int e = blockIdx.x;
    int tid = threadIdx.x;
    for (int f = tid; f < FEAT; f += 128) xr[f] = x[(size_t)e * FEAT + f];
    __syncthreads();
    int d = tid;
    float acc = b1[d];
    for (int kk = 0; kk < FEAT; ++kk) acc += xr[kk] * W1[kk * DD + d];
    acc = fmaxf(acc, 0.0f) * W2[d];
    for (int off = 32; off; off >>= 1) acc += __shfl_down(acc, off, 64);
    if ((tid & 63) == 0) red[tid >> 6] = acc;
    __syncthreads();
    if (tid == 0) {
        float s = red[0] + red[1] + b2[0];
        float lam = fmaxf(s, 0.0f) + log1pf(expf(-fabsf(s)));   // softplus
        lam_out[e] = lam;
        atomicAdd(loss_out, -logf(lam + 1e-8f) * (1.0f / 2048.0f));
    }
}

// ---------------- launch ----------------
extern "C" void kernel_launch(void* const* d_in, const int* in_sizes, int n_in,
                              void* d_out, int out_size, void* d_ws, size_t ws_size,
                              hipStream_t stream) {
    const int*   seq_s = (const int*)d_in[0];
    const int*   seq_o = (const int*)d_in[1];
    const int*   seq_r = (const int*)d_in[2];
    const float* seq_t = (const float*)d_in[3];
    const float* mem0  = (const float*)d_in[4];
    const float* lt0   = (const float*)d_in[5];
    const float* rel   = (const float*)d_in[6];
    const float* W_hidden = (const float*)d_in[7];
    const float* W_hh  = (const float*)d_in[8];
    const float* W_st  = (const float*)d_in[9];
    const float* W_ot  = (const float*)d_in[10];
    const float* Wq    = (const float*)d_in[11];
    const float* Wk    = (const float*)d_in[12];
    const float* Wv    = (const float*)d_in[13];
    const float* Wo    = (const float*)d_in[14];
    const float* sW1   = (const float*)d_in[15];
    const float* sb1   = (const float*)d_in[16];
    const float* sW2   = (const float*)d_in[17];
    const float* sb2   = (const float*)d_in[18];

    float* out      = (float*)d_out;
    float* out_lam  = out + 1;
    float* out_mem  = out + 2049;
    float* out_lt   = out + 2049 + (size_t)NE * DD;

    float* ws = (float*)d_ws;
    float* evt   = ws;                         // 655360
    float* xbuf  = ws + 655360;                // 655360
    float* ebuf  = ws + 1310720;               // 2048*512 = 1048576
    float* qbuf  = ws + 2359296;               // 655360
    float* kbuf  = ws + 3014656;               // 655360
    float* vbuf  = ws + 3670016;               // 655360
    float* aobuf = ws + 4325376;               // 655360
    float* slotDt   = ws + 4980736;            // 4096
    int*   slotPrev = (int*)(ws + 4984832);    // 4096
    int*   slotWin  = (int*)(ws + 4988928);    // 4096
    int*   fixList  = (int*)(ws + 4993024);    // 2048
    int*   fixState = (int*)(ws + 4995072);    // 2048
    int*   evFixIdx = (int*)(ws + 4997120);    // 2048
    int*   fixCnt   = (int*)(ws + 4999168);    // 1

    hipMemsetAsync(fixCnt, 0, sizeof(int), stream);
    hipMemsetAsync(out, 0, sizeof(float), stream);
    hipMemsetAsync(ebuf, 0, (size_t)NEV * INDP * sizeof(float), stream);   // zero K-pad cols

    copy_init<<<2048, 256, 0, stream>>>(mem0, lt0, out_mem, out_lt);

    slot_analyze<<<NSLOT / 4, 256, 0, stream>>>(seq_s, seq_o, seq_t, lt0,
                                                slotDt, slotPrev, slotWin);
    fixlist_build<<<NEV / 256, 256, 0, stream>>>(slotPrev, fixList, fixState,
                                                 evFixIdx, fixCnt);
    event_compute<<<NEV / 8, 256, 0, stream>>>(seq_s, seq_o, seq_r, seq_t, mem0, rel,
                                               W_hidden, W_hh, W_st, W_ot, slotDt,
                                               evt, ebuf);
    for (int r = 0; r < 4; ++r)
        fix_round<<<64, 256, 0, stream>>>(r, seq_s, seq_o, mem0, W_hidden, W_hh,
                                          W_st, W_ot, slotDt, slotPrev,
                                          fixList, fixState, evFixIdx, fixCnt, evt, ebuf);
    scatter_win<<<512, 256, 0, stream>>>(seq_s, seq_o, seq_t, slotWin, evt, out_mem, out_lt);

    for (int l = 0; l < 2; ++l) {
        const float* src = l ? xbuf : evt;     // residual input
        proj<<<dim3(64, 10, 3), 128, 0, stream>>>(ebuf,
                                                  Wq + (size_t)l * IND * FEAT,
                                                  Wk + (size_t)l * IND * FEAT,
                                                  Wv + (size_t)l * IND * FEAT,
                                                  qbuf, kbuf, vbuf);
        attn<<<128, 256, 0, stream>>>(qbuf, kbuf, vbuf, aobuf);
        outproj<<<dim3(64, 10), 128, 0, stream>>>(aobuf, Wo + (size_t)l * FEAT * FEAT,
                                                  src, xbuf, ebuf, (l == 0) ? 1 : 0);
    }
    score_k<<<NEV, 128, 0, stream>>>(xbuf, sW1, sb1, sW2, sb2, out_lam, out);
}

// Round 6
// 558.996 us; speedup vs baseline: 1.3954x; 1.0070x over previous
//
#include <hip/hip_runtime.h>

// ---------------- problem dims ----------------
#define NE   200000
#define DC   64
#define DL   256
#define DD   128
#define FEAT 320          // 2*DD + DC
#define IND  449          // FEAT + DD + 1
#define INDP 512          // ebuf padded row stride (449 -> 512, pad zero-filled)
#define DH   80
#define BB   32
#define TT   64
#define NEV  2048         // BB*TT
#define NSLOT 4096

typedef __attribute__((ext_vector_type(4))) float  floatx4;
typedef __attribute__((ext_vector_type(4), aligned(4))) float floatx4u;   // dword-aligned vec4

__device__ __forceinline__ float sigmoidf_(float x) { return 1.0f / (1.0f + __expf(-x)); }

// ---------------- K0: output-state init copy (mem0 -> out_mem, lt0 -> out_lt) ----------
// out_mem/out_lt sit at byte offset == 4 (mod 16): peel 3 head floats (+1 tail) so
// the float4 STORES are 16B-aligned; loads take the misalignment (cheaper side).
__global__ __launch_bounds__(256)
void copy_init(const float* __restrict__ mem0, const float* __restrict__ lt0,
               float* __restrict__ out_mem, float* __restrict__ out_lt) {
    const size_t NM = (size_t)NE * DD;          // 25,600,000
    const size_t NL = (size_t)NE;               // 200,000
    size_t gid = (size_t)blockIdx.x * 256 + threadIdx.x;
    size_t stride = (size_t)gridDim.x * 256;
    if (gid == 0) {
        out_mem[0] = mem0[0]; out_mem[1] = mem0[1]; out_mem[2] = mem0[2];
        out_mem[NM - 1] = mem0[NM - 1];
        out_lt[0] = lt0[0]; out_lt[1] = lt0[1]; out_lt[2] = lt0[2];
        out_lt[NL - 1] = lt0[NL - 1];
    }
    const size_t nm4 = (NM - 4) / 4;            // 6,399,999 vec4 spans over [3, NM-1)
    const float* __restrict__ sm = mem0 + 3;
    float* __restrict__ dm = out_mem + 3;       // 16B-aligned
    for (size_t i = gid; i < nm4; i += stride) {
        floatx4u v = *(const floatx4u*)&sm[i * 4];   // misaligned load (dword-aligned ok)
        *(floatx4*)&dm[i * 4] = v;                   // aligned store
    }
    const size_t nl4 = (NL - 4) / 4;            // 49,999 vec4 spans over [3, NL-1)
    const float* __restrict__ sl = lt0 + 3;
    float* __restrict__ dl = out_lt + 3;        // 16B-aligned
    for (size_t i = gid; i < nl4; i += stride) {
        floatx4u v = *(const floatx4u*)&sl[i * 4];
        *(floatx4*)&dl[i * 4] = v;
    }
}

// ---------------- K1: slot analysis (prev-toucher, dt, winner) ----------------
__global__ __launch_bounds__(256)
void slot_analyze(const int* __restrict__ seq_s, const int* __restrict__ seq_o,
                  const float* __restrict__ seq_time, const float* __restrict__ lt0,
                  float* __restrict__ slotDt, int* __restrict__ slotPrev,
                  int* __restrict__ slotWin) {
    __shared__ int entL[NSLOT];
    int tid = threadIdx.x;
    for (int j = tid; j < NSLOT; j += 256) {
        int b = j & 31, side = (j >> 5) & 1, t = j >> 6;
        entL[j] = (side ? seq_o : seq_s)[b * TT + t];
    }
    __syncthreads();
    int wave = tid >> 6, lane = tid & 63;
    int slot = blockIdx.x * 4 + wave;
    int t = slot >> 6;
    int myent = entL[slot];
    int win = 1, best = -1;
#pragma unroll 8
    for (int jj = 0; jj < NSLOT / 64; ++jj) {
        int j = jj * 64 + lane;
        if (entL[j] == myent) {
            if (j > slot) win = 0;
            else if ((j >> 6) < t && j > best) best = j;   // keeps max key among prior steps
        }
    }
#pragma unroll
    for (int off = 32; off; off >>= 1) {
        int ob = __shfl_xor(best, off, 64);
        best = best > ob ? best : ob;
    }
    win = __all(win);
    if (lane == 0) {
        int b = slot & 31;
        float tv = seq_time[b * TT + t];
        float pt = (best >= 0) ? seq_time[(best & 31) * TT + (best >> 6)] : lt0[myent];
        slotDt[slot]   = tv - pt;
        slotPrev[slot] = best;
        slotWin[slot]  = win;
    }
}

// ---------------- K1b: build fix list ----------------
__global__ __launch_bounds__(256)
void fixlist_build(const int* __restrict__ slotPrev, int* __restrict__ fixList,
                   int* __restrict__ fixState, int* __restrict__ evFixIdx,
                   int* __restrict__ fixCnt) {
    int e = blockIdx.x * 256 + threadIdx.x;   // 2048 events
    int b = e >> 6, t = e & 63;
    int c = (slotPrev[t * 64 + b] >= 0) | (slotPrev[t * 64 + 32 + b] >= 0);
    int idx = -1;
    if (c) { idx = atomicAdd(fixCnt, 1); fixList[idx] = e; fixState[idx] = -1; }
    evFixIdx[e] = idx;
}

// ---------------- K2: all-events parallel RNN compute (fp32) ----------------
__global__ __launch_bounds__(256)
void event_compute(const int* __restrict__ seq_s, const int* __restrict__ seq_o,
                   const int* __restrict__ seq_r, const float* __restrict__ seq_time,
                   const float* __restrict__ mem0, const float* __restrict__ rel,
                   const float* __restrict__ W_hidden, const float* __restrict__ W_hh,
                   const float* __restrict__ W_st, const float* __restrict__ W_ot,
                   const float* __restrict__ slotDt,
                   float* __restrict__ evt, float* __restrict__ ebuf) {
    __shared__ float xc[8][FEAT];
    __shared__ float hs[8][DL];
    __shared__ int   sSi[8], sOi[8], sRi[8];
    __shared__ float sDs[8], sDo[8], sTv[8];
    int tid = threadIdx.x;
    int e0 = blockIdx.x * 8;
    if (tid < 8) {
        int e = e0 + tid;
        sSi[tid] = seq_s[e]; sOi[tid] = seq_o[e]; sRi[tid] = seq_r[e];
        int b = e >> 6, t = e & 63;
        sDs[tid] = slotDt[t * 64 + b];
        sDo[tid] = slotDt[t * 64 + 32 + b];
        sTv[tid] = seq_time[e];
    }
    __syncthreads();
    for (int i = tid; i < 8 * FEAT; i += 256) {
        int r = i / FEAT, k = i - r * FEAT;
        float v;
        if (k < DD)            v = mem0[(size_t)sSi[r] * DD + k];
        else if (k < 2 * DD)   v = mem0[(size_t)sOi[r] * DD + (k - DD)];
        else                   v = rel[(size_t)sRi[r] * DC + (k - 2 * DD)];
        xc[r][k] = v;
    }
    __syncthreads();
    {   // z = xc @ W_hidden ; h = sigmoid(z)
        int j = tid;
        float acc[8] = {0.f,0.f,0.f,0.f,0.f,0.f,0.f,0.f};
        for (int k = 0; k < FEAT; ++k) {
            float w = W_hidden[(size_t)k * DL + j];
#pragma unroll
            for (int r = 0; r < 8; ++r) acc[r] += xc[r][k] * w;
        }
#pragma unroll
        for (int r = 0; r < 8; ++r) hs[r][j] = sigmoidf_(acc[r]);
    }
    __syncthreads();
    {   // hh = h @ W_hh ; ns/no = sigmoid(dt*W + hh)
        int d = tid & 127, grp = tid >> 7;
        float acc[4] = {0.f,0.f,0.f,0.f};
        for (int l = 0; l < DL; ++l) {
            float w = W_hh[(size_t)l * DD + d];
#pragma unroll
            for (int rr = 0; rr < 4; ++rr) acc[rr] += hs[grp * 4 + rr][l] * w;
        }
        float wst = W_st[d], wot = W_ot[d];
#pragma unroll
        for (int rr = 0; rr < 4; ++rr) {
            int r = grp * 4 + rr;
            int e = e0 + r;
            float ns  = sigmoidf_(sDs[r] * wst + acc[rr]);
            float no_ = sigmoidf_(sDo[r] * wot + acc[rr]);
            evt[(size_t)e * FEAT + d]      = ns;
            evt[(size_t)e * FEAT + DD + d] = no_;
            ebuf[(size_t)e * INDP + d]      = ns;
            ebuf[(size_t)e * INDP + DD + d] = no_;
        }
    }
    for (int i = tid; i < 8 * DC; i += 256) {
        int r = i >> 6, c = i & 63;
        float v = xc[r][2 * DD + c];
        int e = e0 + r;
        evt[(size_t)e * FEAT + 2 * DD + c] = v;
        ebuf[(size_t)e * INDP + 2 * DD + c] = v;
    }
    for (int i = tid; i < 8 * DD; i += 256) {
        int r = i >> 7, d = i & 127;
        float denom = __powf(1.0e4f, (float)d);     // inf for d>=10 -> 1/inf = 0 (matches ref)
        float v = sinf(sTv[r] * (1.0f / denom));
        int e = e0 + r;
        ebuf[(size_t)e * INDP + FEAT + d] = v;
    }
    if (tid < 8) ebuf[(size_t)(e0 + tid) * INDP + FEAT + DD] = 1.0f;
}

// ---------------- K3: fix rounds ----------------
__global__ __launch_bounds__(256)
void fix_round(int round,
               const int* __restrict__ seq_s, const int* __restrict__ seq_o,
               const float* __restrict__ mem0, const float* __restrict__ W_hidden,
               const float* __restrict__ W_hh, const float* __restrict__ W_st,
               const float* __restrict__ W_ot, const float* __restrict__ slotDt,
               const int* __restrict__ slotPrev, const int* __restrict__ fixList,
               int* __restrict__ fixState, const int* __restrict__ evFixIdx,
               const int* __restrict__ fixCnt,
               float* __restrict__ evt, float* __restrict__ ebuf) {
    __shared__ float xc[FEAT];
    __shared__ float hsv[DL];
    __shared__ float hp[2][DD];
    __shared__ int sGo, sPs, sPo, sE;
    int tid = threadIdx.x;
    int n = *fixCnt;
    for (int f = blockIdx.x; f < n; f += gridDim.x) {
        if (tid == 0) {
            int go = 0, ps = 0, po = 0, e = 0;
            if (fixState[f] == -1) {
                e = fixList[f];
                int b = e >> 6, t = e & 63;
                ps = slotPrev[t * 64 + b];
                po = slotPrev[t * 64 + 32 + b];
                go = 1;
                if (ps >= 0) {
                    int pe = (ps & 31) * 64 + (ps >> 6);
                    int fi = evFixIdx[pe];
                    if (fi >= 0) { int st = fixState[fi]; if (st < 0 || st >= round) go = 0; }
                }
                if (po >= 0) {
                    int pe = (po & 31) * 64 + (po >> 6);
                    int fi = evFixIdx[pe];
                    if (fi >= 0) { int st = fixState[fi]; if (st < 0 || st >= round) go = 0; }
                }
            }
            sGo = go; sPs = ps; sPo = po; sE = e;
        }
        __syncthreads();
        int go = sGo, ps = sPs, po = sPo, e = sE;
        __syncthreads();
        if (!go) continue;
        int b = e >> 6, t = e & 63;
        for (int i = tid; i < FEAT; i += 256) {
            float v;
            if (i < DD) {
                v = (ps >= 0) ? evt[(size_t)((ps & 31) * 64 + (ps >> 6)) * FEAT + ((ps >> 5) & 1) * DD + i]
                              : mem0[(size_t)seq_s[e] * DD + i];
            } else if (i < 2 * DD) {
                int k = i - DD;
                v = (po >= 0) ? evt[(size_t)((po & 31) * 64 + (po >> 6)) * FEAT + ((po >> 5) & 1) * DD + k]
                              : mem0[(size_t)seq_o[e] * DD + k];
            } else {
                v = evt[(size_t)e * FEAT + i];
            }
            xc[i] = v;
        }
        __syncthreads();
        {
            float a0 = 0.f, a1 = 0.f, a2 = 0.f, a3 = 0.f;
            for (int k = 0; k < FEAT; k += 4) {
                a0 += xc[k]     * W_hidden[(size_t)k * DL + tid];
                a1 += xc[k + 1] * W_hidden[(size_t)(k + 1) * DL + tid];
                a2 += xc[k + 2] * W_hidden[(size_t)(k + 2) * DL + tid];
                a3 += xc[k + 3] * W_hidden[(size_t)(k + 3) * DL + tid];
            }
            hsv[tid] = sigmoidf_((a0 + a1) + (a2 + a3));
        }
        __syncthreads();
        {
            int d = tid & 127, g = tid >> 7;
            float a0 = 0.f, a1 = 0.f;
            int l0 = g * 128;
            for (int l = 0; l < 128; l += 2) {
                a0 += hsv[l0 + l]     * W_hh[(size_t)(l0 + l) * DD + d];
                a1 += hsv[l0 + l + 1] * W_hh[(size_t)(l0 + l + 1) * DD + d];
            }
            hp[g][d] = a0 + a1;
        }
        __syncthreads();
        if (tid < DD) {
            float hh = hp[0][tid] + hp[1][tid];
            float ns  = sigmoidf_(slotDt[t * 64 + b]      * W_st[tid] + hh);
            float no_ = sigmoidf_(slotDt[t * 64 + 32 + b] * W_ot[tid] + hh);
            evt[(size_t)e * FEAT + tid]      = ns;
            evt[(size_t)e * FEAT + DD + tid] = no_;
            ebuf[(size_t)e * INDP + tid]      = ns;
            ebuf[(size_t)e * INDP + DD + tid] = no_;
        }
        __syncthreads();
        __threadfence();
        if (tid == 0) fixState[f] = round;
        __syncthreads();
    }
}

// ---------------- K4: winner scatter to out_mem / out_lt ----------------
__global__ __launch_bounds__(256)
void scatter_win(const int* __restrict__ seq_s, const int* __restrict__ seq_o,
                 const float* __restrict__ seq_time, const int* __restrict__ slotWin,
                 const float* __restrict__ evt, float* __restrict__ out_mem,
                 float* __restrict__ out_lt) {
    int gid = blockIdx.x * 256 + threadIdx.x;   // 131072 = 4096 slots * 32
    int slot = gid >> 5, c = gid & 31;
    if (!slotWin[slot]) return;
    int b = slot & 31, side = (slot >> 5) & 1, t = slot >> 6;
    int e = b * TT + t;
    int ent = (side ? seq_o : seq_s)[e];
    floatx4 v = *(const floatx4*)&evt[(size_t)e * FEAT + side * DD + c * 4];
    *(floatx4u*)&out_mem[(size_t)ent * DD + c * 4] = v;
    if (c == 0) out_lt[ent] = seq_time[e];
}

// ---------------- phase 2: split-K latency-optimized GEMMs ----------------
// proj: C[2048][320] = A[2048][512(INDP)] @ W[449][320] for z in {q,k,v}.
__global__ __launch_bounds__(128)
void proj(const float* __restrict__ ebuf, const float* __restrict__ Wq,
          const float* __restrict__ Wk, const float* __restrict__ Wv,
          float* __restrict__ q, float* __restrict__ k, float* __restrict__ v) {
    __shared__ float AsT[2][32][33];   // [wave][kk][r]
    __shared__ float Bs[2][32][36];    // [wave][kk][c]
    __shared__ float comb[32][36];
    const float* W = (blockIdx.z == 0) ? Wq : (blockIdx.z == 1) ? Wk : Wv;
    float* out = (blockIdx.z == 0) ? q : (blockIdx.z == 1) ? k : v;
    int tid = threadIdx.x;
    int w = tid >> 6, lane = tid & 63;
    int row0 = blockIdx.x * 32, col0 = blockIdx.y * 32;
    int tx = lane & 7, ty = lane >> 3;
    const int sr = lane >> 3, sk4 = (lane & 7) * 4;
    const int IT0 = w * 8, IT1 = IT0 + 8;       // 16 iters total (K=512 padded)
    floatx4 aR[4], bR[4], acc[4];
#pragma unroll
    for (int i = 0; i < 4; ++i) acc[i] = (floatx4){0.f, 0.f, 0.f, 0.f};
#pragma unroll
    for (int m = 0; m < 4; ++m) {
        int r = m * 8 + sr;
        int kg = IT0 * 32 + r;
        aR[m] = *(const floatx4*)&ebuf[(size_t)(row0 + r) * INDP + IT0 * 32 + sk4];
        bR[m] = (kg < IND) ? *(const floatx4*)&W[(size_t)kg * FEAT + col0 + sk4]
                           : (floatx4){0.f, 0.f, 0.f, 0.f};
    }
    for (int it = IT0; it < IT1; ++it) {
        __syncthreads();
#pragma unroll
        for (int m = 0; m < 4; ++m) {
            int r = m * 8 + sr;
            AsT[w][sk4 + 0][r] = aR[m][0];
            AsT[w][sk4 + 1][r] = aR[m][1];
            AsT[w][sk4 + 2][r] = aR[m][2];
            AsT[w][sk4 + 3][r] = aR[m][3];
            *(floatx4*)&Bs[w][r][sk4] = bR[m];
        }
        __syncthreads();
        if (it + 1 < IT1) {                      // prefetch next tile (overlaps compute)
            int k0n = (it + 1) * 32;
#pragma unroll
            for (int m = 0; m < 4; ++m) {
                int r = m * 8 + sr;
                int kg = k0n + r;
                aR[m] = *(const floatx4*)&ebuf[(size_t)(row0 + r) * INDP + k0n + sk4];
                bR[m] = (kg < IND) ? *(const floatx4*)&W[(size_t)kg * FEAT + col0 + sk4]
                                   : (floatx4){0.f, 0.f, 0.f, 0.f};
            }
        }
#pragma unroll
        for (int kk = 0; kk < 32; ++kk) {
            floatx4 a = *(const floatx4*)&AsT[w][kk][ty * 4];
            floatx4 b = *(const floatx4*)&Bs[w][kk][tx * 4];
#pragma unroll
            for (int i = 0; i < 4; ++i) acc[i] += a[i] * b;
        }
    }
    if (w == 1) {
#pragma unroll
        for (int i = 0; i < 4; ++i)
            *(floatx4*)&comb[ty * 4 + i][tx * 4] = acc[i];
    }
    __syncthreads();
    if (w == 0) {
#pragma unroll
        for (int i = 0; i < 4; ++i) {
            floatx4 p = *(const floatx4*)&comb[ty * 4 + i][tx * 4];
            floatx4 s = acc[i] + p;
            *(floatx4*)&out[(size_t)(row0 + ty * 4 + i) * FEAT + col0 + tx * 4] = s;
        }
    }
}

// outproj: acc = A[2048][320] @ Wo[320][320]; x = resid + tanh(acc); optional ebuf write.
__global__ __launch_bounds__(128)
void outproj(const float* __restrict__ ain, const float* __restrict__ Wo,
             const float* __restrict__ resid, float* __restrict__ xout,
             float* __restrict__ ebufW, int writeE) {
    __shared__ float AsT[2][32][33];
    __shared__ float Bs[2][32][36];
    __shared__ float comb[32][36];
    int tid = threadIdx.x;
    int w = tid >> 6, lane = tid & 63;
    int row0 = blockIdx.x * 32, col0 = blockIdx.y * 32;
    int tx = lane & 7, ty = lane >> 3;
    const int sr = lane >> 3, sk4 = (lane & 7) * 4;
    const int IT0 = w * 5, IT1 = IT0 + 5;       // 10 iters total (K=320 exact)
    floatx4 aR[4], bR[4], acc[4];
#pragma unroll
    for (int i = 0; i < 4; ++i) acc[i] = (floatx4){0.f, 0.f, 0.f, 0.f};
#pragma unroll
    for (int m = 0; m < 4; ++m) {
        int r = m * 8 + sr;
        aR[m] = *(const floatx4*)&ain[(size_t)(row0 + r) * FEAT + IT0 * 32 + sk4];
        bR[m] = *(const floatx4*)&Wo[(size_t)(IT0 * 32 + r) * FEAT + col0 + sk4];
    }
    for (int it = IT0; it < IT1; ++it) {
        __syncthreads();
#pragma unroll
        for (int m = 0; m < 4; ++m) {
            int r = m * 8 + sr;
            AsT[w][sk4 + 0][r] = aR[m][0];
            AsT[w][sk4 + 1][r] = aR[m][1];
            AsT[w][sk4 + 2][r] = aR[m][2];
            AsT[w][sk4 + 3][r] = aR[m][3];
            *(floatx4*)&Bs[w][r][sk4] = bR[m];
        }
        __syncthreads();
        if (it + 1 < IT1) {
            int k0n = (it + 1) * 32;
#pragma unroll
            for (int m = 0; m < 4; ++m) {
                int r = m * 8 + sr;
                aR[m] = *(const floatx4*)&ain[(size_t)(row0 + r) * FEAT + k0n + sk4];
                bR[m] = *(const floatx4*)&Wo[(size_t)(k0n + r) * FEAT + col0 + sk4];
            }
        }
#pragma unroll
        for (int kk = 0; kk < 32; ++kk) {
            floatx4 a = *(const floatx4*)&AsT[w][kk][ty * 4];
            floatx4 b = *(const floatx4*)&Bs[w][kk][tx * 4];
#pragma unroll
            for (int i = 0; i < 4; ++i) acc[i] += a[i] * b;
        }
    }
    if (w == 1) {
#pragma unroll
        for (int i = 0; i < 4; ++i)
            *(floatx4*)&comb[ty * 4 + i][tx * 4] = acc[i];
    }
    __syncthreads();
    if (w == 0) {
#pragma unroll
        for (int i = 0; i < 4; ++i) {
            int row = row0 + ty * 4 + i;
            int c0 = col0 + tx * 4;
            floatx4 p = *(const floatx4*)&comb[ty * 4 + i][tx * 4];
            floatx4 a = acc[i] + p;
            floatx4 res = *(const floatx4*)&resid[(size_t)row * FEAT + c0];
            floatx4 o;
#pragma unroll
            for (int j = 0; j < 4; ++j) o[j] = res[j] + tanhf(a[j]);
            *(floatx4*)&xout[(size_t)row * FEAT + c0] = o;
            if (writeE) *(floatx4*)&ebufW[(size_t)row * INDP + c0] = o;
        }
    }
}

__global__ __launch_bounds__(256)
void attn(const float* __restrict__ q, const float* __restrict__ k,
          const float* __restrict__ v, float* __restrict__ ao) {
    __shared__ float qs[TT][DH], ks[TT][DH], vs[TT][DH];
    __shared__ float sc[TT][TT + 1];
    int bh = blockIdx.x;
    int b = bh >> 2, h = bh & 3;
    int tid = threadIdx.x;
    for (int i = tid; i < TT * DH; i += 256) {
        int r = i / DH, d = i - r * DH;
        size_t base = (size_t)(b * TT + r) * FEAT + h * DH + d;
        qs[r][d] = q[base]; ks[r][d] = k[base]; vs[r][d] = v[base];
    }
    __syncthreads();
    const float scale = 0.11180339887498949f;   // 1/sqrt(80)
    for (int idx = tid; idx < TT * TT; idx += 256) {
        int i = idx >> 6, j = idx & 63;
        float s = 0.f;
        for (int d = 0; d < DH; ++d) s += qs[i][d] * ks[j][d];
        sc[i][j] = s * scale;
    }
    __syncthreads();
    if (tid < TT) {
        int i = tid;
        if (i == 0) {
            for (int j = 0; j < TT; ++j) sc[0][j] = 0.0f;
        } else {
            float m = -1e30f;
            for (int j = 0; j < i; ++j) m = fmaxf(m, sc[i][j]);
            float sum = 0.f;
            for (int j = 0; j < i; ++j) { float p = __expf(sc[i][j] - m); sc[i][j] = p; sum += p; }
            float inv = 1.0f / sum;
            for (int j = 0; j < i; ++j) sc[i][j] *= inv;
            for (int j = i; j < TT; ++j) sc[i][j] = 0.0f;
        }
    }
    __syncthreads();
    for (int idx = tid; idx < TT * DH; idx += 256) {
        int i = idx / DH, d = idx - i * DH;
        float s = 0.f;
        for (int j = 0; j < TT; ++j) s += sc[i][j] * vs[j][d];
        ao[(size_t)(b * TT + i) * FEAT + h * DH + d] = s;
    }
}

__global__ __launch_bounds__(128)
void score_k(const float* __restrict__ x, const float* __restrict__ W1,
             const float* __restrict__ b1, const float* __restrict__ W2,
             const float* __restrict__ b2, float* __restrict__ lam_out,
             float* __restrict__ loss_out) {
    __shared__ float xr[FEAT];
    __shared__ float red[2];
    int e = blockIdx.x;
    int tid = threadIdx.x;
    for (int f = tid; f < FEAT; f += 128) xr[f] = x[(size_t)e * FEAT + f];
    __syncthreads();
    int d = tid;
    float acc = b1[d];
    for (int kk = 0; kk < FEAT; ++kk) acc += xr[kk] * W1[kk * DD + d];
    acc = fmaxf(acc, 0.0f) * W2[d];
    for (int off = 32; off; off >>= 1) acc += __shfl_down(acc, off, 64);
    if ((tid & 63) == 0) red[tid >> 6] = acc;
    __syncthreads();
    if (tid == 0) {
        float s = red[0] + red[1] + b2[0];
        float lam = fmaxf(s, 0.0f) + log1pf(expf(-fabsf(s)));   // softplus
        lam_out[e] = lam;
        atomicAdd(loss_out, -logf(lam + 1e-8f) * (1.0f / 2048.0f));
    }
}

// ---------------- launch ----------------
extern "C" void kernel_launch(void* const* d_in, const int* in_sizes, int n_in,
                              void* d_out, int out_size, void* d_ws, size_t ws_size,
                              hipStream_t stream) {
    const int*   seq_s = (const int*)d_in[0];
    const int*   seq_o = (const int*)d_in[1];
    const int*   seq_r = (const int*)d_in[2];
    const float* seq_t = (const float*)d_in[3];
    const float* mem0  = (const float*)d_in[4];
    const float* lt0   = (const float*)d_in[5];
    const float* rel   = (const float*)d_in[6];
    const float* W_hidden = (const float*)d_in[7];
    const float* W_hh  = (const float*)d_in[8];
    const float* W_st  = (const float*)d_in[9];
    const float* W_ot  = (const float*)d_in[10];
    const float* Wq    = (const float*)d_in[11];
    const float* Wk    = (const float*)d_in[12];
    const float* Wv    = (const float*)d_in[13];
    const float* Wo    = (const float*)d_in[14];
    const float* sW1   = (const float*)d_in[15];
    const float* sb1   = (const float*)d_in[16];
    const float* sW2   = (const float*)d_in[17];
    const float* sb2   = (const float*)d_in[18];

    float* out      = (float*)d_out;
    float* out_lam  = out + 1;
    float* out_mem  = out + 2049;
    float* out_lt   = out + 2049 + (size_t)NE * DD;

    float* ws = (float*)d_ws;
    float* evt   = ws;                         // 655360
    float* xbuf  = ws + 655360;                // 655360
    float* ebuf  = ws + 1310720;               // 2048*512 = 1048576
    float* qbuf  = ws + 2359296;               // 655360
    float* kbuf  = ws + 3014656;               // 655360
    float* vbuf  = ws + 3670016;               // 655360
    float* aobuf = ws + 4325376;               // 655360
    float* slotDt   = ws + 4980736;            // 4096
    int*   slotPrev = (int*)(ws + 4984832);    // 4096
    int*   slotWin  = (int*)(ws + 4988928);    // 4096
    int*   fixList  = (int*)(ws + 4993024);    // 2048
    int*   fixState = (int*)(ws + 4995072);    // 2048
    int*   evFixIdx = (int*)(ws + 4997120);    // 2048
    int*   fixCnt   = (int*)(ws + 4999168);    // 1

    hipMemsetAsync(fixCnt, 0, sizeof(int), stream);
    hipMemsetAsync(out, 0, sizeof(float), stream);
    hipMemsetAsync(ebuf, 0, (size_t)NEV * INDP * sizeof(float), stream);   // zero K-pad cols

    copy_init<<<2048, 256, 0, stream>>>(mem0, lt0, out_mem, out_lt);

    slot_analyze<<<NSLOT / 4, 256, 0, stream>>>(seq_s, seq_o, seq_t, lt0,
                                                slotDt, slotPrev, slotWin);
    fixlist_build<<<NEV / 256, 256, 0, stream>>>(slotPrev, fixList, fixState,
                                                 evFixIdx, fixCnt);
    event_compute<<<NEV / 8, 256, 0, stream>>>(seq_s, seq_o, seq_r, seq_t, mem0, rel,
                                               W_hidden, W_hh, W_st, W_ot, slotDt,
                                               evt, ebuf);
    for (int r = 0; r < 4; ++r)
        fix_round<<<64, 256, 0, stream>>>(r, seq_s, seq_o, mem0, W_hidden, W_hh,
                                          W_st, W_ot, slotDt, slotPrev,
                                          fixList, fixState, evFixIdx, fixCnt, evt, ebuf);
    scatter_win<<<512, 256, 0, stream>>>(seq_s, seq_o, seq_t, slotWin, evt, out_mem, out_lt);

    for (int l = 0; l < 2; ++l) {
        const float* src = l ? xbuf : evt;     // residual input
        proj<<<dim3(64, 10, 3), 128, 0, stream>>>(ebuf,
                                                  Wq + (size_t)l * IND * FEAT,
                                                  Wk + (size_t)l * IND * FEAT,
                                                  Wv + (size_t)l * IND * FEAT,
                                                  qbuf, kbuf, vbuf);
        attn<<<128, 256, 0, stream>>>(qbuf, kbuf, vbuf, aobuf);
        outproj<<<dim3(64, 10), 128, 0, stream>>>(aobuf, Wo + (size_t)l * FEAT * FEAT,
                                                  src, xbuf, ebuf, (l == 0) ? 1 : 0);
    }
    score_k<<<NEV, 128, 0, stream>>>(xbuf, sW1, sb1, sW2, sb2, out_lam, out);
}

// Round 7
// 558.023 us; speedup vs baseline: 1.3978x; 1.0017x over previous
//
#include <hip/hip_runtime.h>

// ---------------- problem dims ----------------
#define NE   200000
#define DC   64
#define DL   256
#define DD   128
#define FEAT 320          // 2*DD + DC
#define IND  449          // FEAT + DD + 1
#define INDP 512          // ebuf padded row stride (449 -> 512, pad zero-filled)
#define DH   80
#define BB   32
#define TT   64
#define NEV  2048         // BB*TT
#define NSLOT 4096

typedef __attribute__((ext_vector_type(4))) float  floatx4;
typedef __attribute__((ext_vector_type(4), aligned(4))) float floatx4u;   // dword-aligned vec4

__device__ __forceinline__ float sigmoidf_(float x) { return 1.0f / (1.0f + __expf(-x)); }

// ---------------- K0: output-state init copy (mem0 -> out_mem, lt0 -> out_lt) ----------
// out_mem/out_lt are +4B (mod 16) relative to the aligned sources, so a direct copy
// always has one misaligned side (measured: caps at ~2.5 TB/s vs 6.3 achievable).
// Fix: TWO aligned vec4 loads + register recombine -> one aligned vec4 store.
// Adjacent-thread load overlap (16B) is an L1 hit; HBM traffic unchanged.
__global__ __launch_bounds__(256)
void copy_init(const float* __restrict__ mem0, const float* __restrict__ lt0,
               float* __restrict__ out_mem, float* __restrict__ out_lt) {
    const size_t NM = (size_t)NE * DD;          // 25,600,000
    const size_t NL = (size_t)NE;               // 200,000
    size_t gid = (size_t)blockIdx.x * 256 + threadIdx.x;
    size_t stride = (size_t)gridDim.x * 256;
    if (gid == 0) {
        out_mem[0] = mem0[0]; out_mem[1] = mem0[1]; out_mem[2] = mem0[2];
        out_mem[NM - 1] = mem0[NM - 1];
        out_lt[0] = lt0[0]; out_lt[1] = lt0[1]; out_lt[2] = lt0[2];
        out_lt[NL - 1] = lt0[NL - 1];
    }
    const size_t nm4 = (NM - 4) / 4;            // 6,399,999 vec4 stores over [3, NM-1)
    float* __restrict__ dm = out_mem + 3;       // 16B-aligned
    for (size_t i = gid; i < nm4; i += stride) {
        floatx4 lo = *(const floatx4*)&mem0[i * 4];        // aligned
        floatx4 hi = *(const floatx4*)&mem0[i * 4 + 4];    // aligned (max elem NM-1)
        floatx4 o = {lo[3], hi[0], hi[1], hi[2]};          // elems 4i+3 .. 4i+6
        *(floatx4*)&dm[i * 4] = o;                         // aligned store
    }
    const size_t nl4 = (NL - 4) / 4;            // 49,999
    float* __restrict__ dl = out_lt + 3;        // 16B-aligned
    for (size_t i = gid; i < nl4; i += stride) {
        floatx4 lo = *(const floatx4*)&lt0[i * 4];
        floatx4 hi = *(const floatx4*)&lt0[i * 4 + 4];
        floatx4 o = {lo[3], hi[0], hi[1], hi[2]};
        *(floatx4*)&dl[i * 4] = o;
    }
}

// ---------------- K1: slot analysis (prev-toucher, dt, winner) ----------------
__global__ __launch_bounds__(256)
void slot_analyze(const int* __restrict__ seq_s, const int* __restrict__ seq_o,
                  const float* __restrict__ seq_time, const float* __restrict__ lt0,
                  float* __restrict__ slotDt, int* __restrict__ slotPrev,
                  int* __restrict__ slotWin) {
    __shared__ int entL[NSLOT];
    int tid = threadIdx.x;
    for (int j = tid; j < NSLOT; j += 256) {
        int b = j & 31, side = (j >> 5) & 1, t = j >> 6;
        entL[j] = (side ? seq_o : seq_s)[b * TT + t];
    }
    __syncthreads();
    int wave = tid >> 6, lane = tid & 63;
    int slot = blockIdx.x * 4 + wave;
    int t = slot >> 6;
    int myent = entL[slot];
    int win = 1, best = -1;
#pragma unroll 8
    for (int jj = 0; jj < NSLOT / 64; ++jj) {
        int j = jj * 64 + lane;
        if (entL[j] == myent) {
            if (j > slot) win = 0;
            else if ((j >> 6) < t && j > best) best = j;   // keeps max key among prior steps
        }
    }
#pragma unroll
    for (int off = 32; off; off >>= 1) {
        int ob = __shfl_xor(best, off, 64);
        best = best > ob ? best : ob;
    }
    win = __all(win);
    if (lane == 0) {
        int b = slot & 31;
        float tv = seq_time[b * TT + t];
        float pt = (best >= 0) ? seq_time[(best & 31) * TT + (best >> 6)] : lt0[myent];
        slotDt[slot]   = tv - pt;
        slotPrev[slot] = best;
        slotWin[slot]  = win;
    }
}

// ---------------- K1b: build fix list ----------------
__global__ __launch_bounds__(256)
void fixlist_build(const int* __restrict__ slotPrev, int* __restrict__ fixList,
                   int* __restrict__ fixState, int* __restrict__ evFixIdx,
                   int* __restrict__ fixCnt) {
    int e = blockIdx.x * 256 + threadIdx.x;   // 2048 events
    int b = e >> 6, t = e & 63;
    int c = (slotPrev[t * 64 + b] >= 0) | (slotPrev[t * 64 + 32 + b] >= 0);
    int idx = -1;
    if (c) { idx = atomicAdd(fixCnt, 1); fixList[idx] = e; fixState[idx] = -1; }
    evFixIdx[e] = idx;
}

// ---------------- K2: all-events parallel RNN compute (fp32) ----------------
__global__ __launch_bounds__(256)
void event_compute(const int* __restrict__ seq_s, const int* __restrict__ seq_o,
                   const int* __restrict__ seq_r, const float* __restrict__ seq_time,
                   const float* __restrict__ mem0, const float* __restrict__ rel,
                   const float* __restrict__ W_hidden, const float* __restrict__ W_hh,
                   const float* __restrict__ W_st, const float* __restrict__ W_ot,
                   const float* __restrict__ slotDt,
                   float* __restrict__ evt, float* __restrict__ ebuf) {
    __shared__ float xc[8][FEAT];
    __shared__ float hs[8][DL];
    __shared__ int   sSi[8], sOi[8], sRi[8];
    __shared__ float sDs[8], sDo[8], sTv[8];
    int tid = threadIdx.x;
    int e0 = blockIdx.x * 8;
    if (tid < 8) {
        int e = e0 + tid;
        sSi[tid] = seq_s[e]; sOi[tid] = seq_o[e]; sRi[tid] = seq_r[e];
        int b = e >> 6, t = e & 63;
        sDs[tid] = slotDt[t * 64 + b];
        sDo[tid] = slotDt[t * 64 + 32 + b];
        sTv[tid] = seq_time[e];
    }
    __syncthreads();
    for (int i = tid; i < 8 * FEAT; i += 256) {
        int r = i / FEAT, k = i - r * FEAT;
        float v;
        if (k < DD)            v = mem0[(size_t)sSi[r] * DD + k];
        else if (k < 2 * DD)   v = mem0[(size_t)sOi[r] * DD + (k - DD)];
        else                   v = rel[(size_t)sRi[r] * DC + (k - 2 * DD)];
        xc[r][k] = v;
    }
    __syncthreads();
    {   // z = xc @ W_hidden ; h = sigmoid(z)
        int j = tid;
        float acc[8] = {0.f,0.f,0.f,0.f,0.f,0.f,0.f,0.f};
        for (int k = 0; k < FEAT; ++k) {
            float w = W_hidden[(size_t)k * DL + j];
#pragma unroll
            for (int r = 0; r < 8; ++r) acc[r] += xc[r][k] * w;
        }
#pragma unroll
        for (int r = 0; r < 8; ++r) hs[r][j] = sigmoidf_(acc[r]);
    }
    __syncthreads();
    {   // hh = h @ W_hh ; ns/no = sigmoid(dt*W + hh)
        int d = tid & 127, grp = tid >> 7;
        float acc[4] = {0.f,0.f,0.f,0.f};
        for (int l = 0; l < DL; ++l) {
            float w = W_hh[(size_t)l * DD + d];
#pragma unroll
            for (int rr = 0; rr < 4; ++rr) acc[rr] += hs[grp * 4 + rr][l] * w;
        }
        float wst = W_st[d], wot = W_ot[d];
#pragma unroll
        for (int rr = 0; rr < 4; ++rr) {
            int r = grp * 4 + rr;
            int e = e0 + r;
            float ns  = sigmoidf_(sDs[r] * wst + acc[rr]);
            float no_ = sigmoidf_(sDo[r] * wot + acc[rr]);
            evt[(size_t)e * FEAT + d]      = ns;
            evt[(size_t)e * FEAT + DD + d] = no_;
            ebuf[(size_t)e * INDP + d]      = ns;
            ebuf[(size_t)e * INDP + DD + d] = no_;
        }
    }
    for (int i = tid; i < 8 * DC; i += 256) {
        int r = i >> 6, c = i & 63;
        float v = xc[r][2 * DD + c];
        int e = e0 + r;
        evt[(size_t)e * FEAT + 2 * DD + c] = v;
        ebuf[(size_t)e * INDP + 2 * DD + c] = v;
    }
    for (int i = tid; i < 8 * DD; i += 256) {
        int r = i >> 7, d = i & 127;
        float denom = __powf(1.0e4f, (float)d);     // inf for d>=10 -> 1/inf = 0 (matches ref)
        float v = sinf(sTv[r] * (1.0f / denom));
        int e = e0 + r;
        ebuf[(size_t)e * INDP + FEAT + d] = v;
    }
    if (tid < 8) ebuf[(size_t)(e0 + tid) * INDP + FEAT + DD] = 1.0f;
}

// ---------------- K3: fix rounds ----------------
__global__ __launch_bounds__(256)
void fix_round(int round,
               const int* __restrict__ seq_s, const int* __restrict__ seq_o,
               const float* __restrict__ mem0, const float* __restrict__ W_hidden,
               const float* __restrict__ W_hh, const float* __restrict__ W_st,
               const float* __restrict__ W_ot, const float* __restrict__ slotDt,
               const int* __restrict__ slotPrev, const int* __restrict__ fixList,
               int* __restrict__ fixState, const int* __restrict__ evFixIdx,
               const int* __restrict__ fixCnt,
               float* __restrict__ evt, float* __restrict__ ebuf) {
    __shared__ float xc[FEAT];
    __shared__ float hsv[DL];
    __shared__ float hp[2][DD];
    __shared__ int sGo, sPs, sPo, sE;
    int tid = threadIdx.x;
    int n = *fixCnt;
    for (int f = blockIdx.x; f < n; f += gridDim.x) {
        if (tid == 0) {
            int go = 0, ps = 0, po = 0, e = 0;
            if (fixState[f] == -1) {
                e = fixList[f];
                int b = e >> 6, t = e & 63;
                ps = slotPrev[t * 64 + b];
                po = slotPrev[t * 64 + 32 + b];
                go = 1;
                if (ps >= 0) {
                    int pe = (ps & 31) * 64 + (ps >> 6);
                    int fi = evFixIdx[pe];
                    if (fi >= 0) { int st = fixState[fi]; if (st < 0 || st >= round) go = 0; }
                }
                if (po >= 0) {
                    int pe = (po & 31) * 64 + (po >> 6);
                    int fi = evFixIdx[pe];
                    if (fi >= 0) { int st = fixState[fi]; if (st < 0 || st >= round) go = 0; }
                }
            }
            sGo = go; sPs = ps; sPo = po; sE = e;
        }
        __syncthreads();
        int go = sGo, ps = sPs, po = sPo, e = sE;
        __syncthreads();
        if (!go) continue;
        int b = e >> 6, t = e & 63;
        for (int i = tid; i < FEAT; i += 256) {
            float v;
            if (i < DD) {
                v = (ps >= 0) ? evt[(size_t)((ps & 31) * 64 + (ps >> 6)) * FEAT + ((ps >> 5) & 1) * DD + i]
                              : mem0[(size_t)seq_s[e] * DD + i];
            } else if (i < 2 * DD) {
                int k = i - DD;
                v = (po >= 0) ? evt[(size_t)((po & 31) * 64 + (po >> 6)) * FEAT + ((po >> 5) & 1) * DD + k]
                              : mem0[(size_t)seq_o[e] * DD + k];
            } else {
                v = evt[(size_t)e * FEAT + i];
            }
            xc[i] = v;
        }
        __syncthreads();
        {
            float a0 = 0.f, a1 = 0.f, a2 = 0.f, a3 = 0.f;
            for (int k = 0; k < FEAT; k += 4) {
                a0 += xc[k]     * W_hidden[(size_t)k * DL + tid];
                a1 += xc[k + 1] * W_hidden[(size_t)(k + 1) * DL + tid];
                a2 += xc[k + 2] * W_hidden[(size_t)(k + 2) * DL + tid];
                a3 += xc[k + 3] * W_hidden[(size_t)(k + 3) * DL + tid];
            }
            hsv[tid] = sigmoidf_((a0 + a1) + (a2 + a3));
        }
        __syncthreads();
        {
            int d = tid & 127, g = tid >> 7;
            float a0 = 0.f, a1 = 0.f;
            int l0 = g * 128;
            for (int l = 0; l < 128; l += 2) {
                a0 += hsv[l0 + l]     * W_hh[(size_t)(l0 + l) * DD + d];
                a1 += hsv[l0 + l + 1] * W_hh[(size_t)(l0 + l + 1) * DD + d];
            }
            hp[g][d] = a0 + a1;
        }
        __syncthreads();
        if (tid < DD) {
            float hh = hp[0][tid] + hp[1][tid];
            float ns  = sigmoidf_(slotDt[t * 64 + b]      * W_st[tid] + hh);
            float no_ = sigmoidf_(slotDt[t * 64 + 32 + b] * W_ot[tid] + hh);
            evt[(size_t)e * FEAT + tid]      = ns;
            evt[(size_t)e * FEAT + DD + tid] = no_;
            ebuf[(size_t)e * INDP + tid]      = ns;
            ebuf[(size_t)e * INDP + DD + tid] = no_;
        }
        __syncthreads();
        __threadfence();
        if (tid == 0) fixState[f] = round;
        __syncthreads();
    }
}

// ---------------- K4: winner scatter to out_mem / out_lt ----------------
__global__ __launch_bounds__(256)
void scatter_win(const int* __restrict__ seq_s, const int* __restrict__ seq_o,
                 const float* __restrict__ seq_time, const int* __restrict__ slotWin,
                 const float* __restrict__ evt, float* __restrict__ out_mem,
                 float* __restrict__ out_lt) {
    int gid = blockIdx.x * 256 + threadIdx.x;   // 131072 = 4096 slots * 32
    int slot = gid >> 5, c = gid & 31;
    if (!slotWin[slot]) return;
    int b = slot & 31, side = (slot >> 5) & 1, t = slot >> 6;
    int e = b * TT + t;
    int ent = (side ? seq_o : seq_s)[e];
    floatx4 v = *(const floatx4*)&evt[(size_t)e * FEAT + side * DD + c * 4];
    *(floatx4u*)&out_mem[(size_t)ent * DD + c * 4] = v;
    if (c == 0) out_lt[ent] = seq_time[e];
}

// ---------------- phase 2: split-K latency-optimized GEMMs ----------------
// proj: C[2048][320] = A[2048][512(INDP)] @ W[449][320] for z in {q,k,v}.
__global__ __launch_bounds__(128)
void proj(const float* __restrict__ ebuf, const float* __restrict__ Wq,
          const float* __restrict__ Wk, const float* __restrict__ Wv,
          float* __restrict__ q, float* __restrict__ k, float* __restrict__ v) {
    __shared__ float AsT[2][32][33];   // [wave][kk][r]
    __shared__ float Bs[2][32][36];    // [wave][kk][c]
    __shared__ float comb[32][36];
    const float* W = (blockIdx.z == 0) ? Wq : (blockIdx.z == 1) ? Wk : Wv;
    float* out = (blockIdx.z == 0) ? q : (blockIdx.z == 1) ? k : v;
    int tid = threadIdx.x;
    int w = tid >> 6, lane = tid & 63;
    int row0 = blockIdx.x * 32, col0 = blockIdx.y * 32;
    int tx = lane & 7, ty = lane >> 3;
    const int sr = lane >> 3, sk4 = (lane & 7) * 4;
    const int IT0 = w * 8, IT1 = IT0 + 8;       // 16 iters total (K=512 padded)
    floatx4 aR[4], bR[4], acc[4];
#pragma unroll
    for (int i = 0; i < 4; ++i) acc[i] = (floatx4){0.f, 0.f, 0.f, 0.f};
#pragma unroll
    for (int m = 0; m < 4; ++m) {
        int r = m * 8 + sr;
        int kg = IT0 * 32 + r;
        aR[m] = *(const floatx4*)&ebuf[(size_t)(row0 + r) * INDP + IT0 * 32 + sk4];
        bR[m] = (kg < IND) ? *(const floatx4*)&W[(size_t)kg * FEAT + col0 + sk4]
                           : (floatx4){0.f, 0.f, 0.f, 0.f};
    }
    for (int it = IT0; it < IT1; ++it) {
        __syncthreads();
#pragma unroll
        for (int m = 0; m < 4; ++m) {
            int r = m * 8 + sr;
            AsT[w][sk4 + 0][r] = aR[m][0];
            AsT[w][sk4 + 1][r] = aR[m][1];
            AsT[w][sk4 + 2][r] = aR[m][2];
            AsT[w][sk4 + 3][r] = aR[m][3];
            *(floatx4*)&Bs[w][r][sk4] = bR[m];
        }
        __syncthreads();
        if (it + 1 < IT1) {                      // prefetch next tile (overlaps compute)
            int k0n = (it + 1) * 32;
#pragma unroll
            for (int m = 0; m < 4; ++m) {
                int r = m * 8 + sr;
                int kg = k0n + r;
                aR[m] = *(const floatx4*)&ebuf[(size_t)(row0 + r) * INDP + k0n + sk4];
                bR[m] = (kg < IND) ? *(const floatx4*)&W[(size_t)kg * FEAT + col0 + sk4]
                                   : (floatx4){0.f, 0.f, 0.f, 0.f};
            }
        }
#pragma unroll
        for (int kk = 0; kk < 32; ++kk) {
            floatx4 a = *(const floatx4*)&AsT[w][kk][ty * 4];
            floatx4 b = *(const floatx4*)&Bs[w][kk][tx * 4];
#pragma unroll
            for (int i = 0; i < 4; ++i) acc[i] += a[i] * b;
        }
    }
    if (w == 1) {
#pragma unroll
        for (int i = 0; i < 4; ++i)
            *(floatx4*)&comb[ty * 4 + i][tx * 4] = acc[i];
    }
    __syncthreads();
    if (w == 0) {
#pragma unroll
        for (int i = 0; i < 4; ++i) {
            floatx4 p = *(const floatx4*)&comb[ty * 4 + i][tx * 4];
            floatx4 s = acc[i] + p;
            *(floatx4*)&out[(size_t)(row0 + ty * 4 + i) * FEAT + col0 + tx * 4] = s;
        }
    }
}

// outproj: acc = A[2048][320] @ Wo[320][320]; x = resid + tanh(acc); optional ebuf write.
__global__ __launch_bounds__(128)
void outproj(const float* __restrict__ ain, const float* __restrict__ Wo,
             const float* __restrict__ resid, float* __restrict__ xout,
             float* __restrict__ ebufW, int writeE) {
    __shared__ float AsT[2][32][33];
    __shared__ float Bs[2][32][36];
    __shared__ float comb[32][36];
    int tid = threadIdx.x;
    int w = tid >> 6, lane = tid & 63;
    int row0 = blockIdx.x * 32, col0 = blockIdx.y * 32;
    int tx = lane & 7, ty = lane >> 3;
    const int sr = lane >> 3, sk4 = (lane & 7) * 4;
    const int IT0 = w * 5, IT1 = IT0 + 5;       // 10 iters total (K=320 exact)
    floatx4 aR[4], bR[4], acc[4];
#pragma unroll
    for (int i = 0; i < 4; ++i) acc[i] = (floatx4){0.f, 0.f, 0.f, 0.f};
#pragma unroll
    for (int m = 0; m < 4; ++m) {
        int r = m * 8 + sr;
        aR[m] = *(const floatx4*)&ain[(size_t)(row0 + r) * FEAT + IT0 * 32 + sk4];
        bR[m] = *(const floatx4*)&Wo[(size_t)(IT0 * 32 + r) * FEAT + col0 + sk4];
    }
    for (int it = IT0; it < IT1; ++it) {
        __syncthreads();
#pragma unroll
        for (int m = 0; m < 4; ++m) {
            int r = m * 8 + sr;
            AsT[w][sk4 + 0][r] = aR[m][0];
            AsT[w][sk4 + 1][r] = aR[m][1];
            AsT[w][sk4 + 2][r] = aR[m][2];
            AsT[w][sk4 + 3][r] = aR[m][3];
            *(floatx4*)&Bs[w][r][sk4] = bR[m];
        }
        __syncthreads();
        if (it + 1 < IT1) {
            int k0n = (it + 1) * 32;
#pragma unroll
            for (int m = 0; m < 4; ++m) {
                int r = m * 8 + sr;
                aR[m] = *(const floatx4*)&ain[(size_t)(row0 + r) * FEAT + k0n + sk4];
                bR[m] = *(const floatx4*)&Wo[(size_t)(k0n + r) * FEAT + col0 + sk4];
            }
        }
#pragma unroll
        for (int kk = 0; kk < 32; ++kk) {
            floatx4 a = *(const floatx4*)&AsT[w][kk][ty * 4];
            floatx4 b = *(const floatx4*)&Bs[w][kk][tx * 4];
#pragma unroll
            for (int i = 0; i < 4; ++i) acc[i] += a[i] * b;
        }
    }
    if (w == 1) {
#pragma unroll
        for (int i = 0; i < 4; ++i)
            *(floatx4*)&comb[ty * 4 + i][tx * 4] = acc[i];
    }
    __syncthreads();
    if (w == 0) {
#pragma unroll
        for (int i = 0; i < 4; ++i) {
            int row = row0 + ty * 4 + i;
            int c0 = col0 + tx * 4;
            floatx4 p = *(const floatx4*)&comb[ty * 4 + i][tx * 4];
            floatx4 a = acc[i] + p;
            floatx4 res = *(const floatx4*)&resid[(size_t)row * FEAT + c0];
            floatx4 o;
#pragma unroll
            for (int j = 0; j < 4; ++j) o[j] = res[j] + tanhf(a[j]);
            *(floatx4*)&xout[(size_t)row * FEAT + c0] = o;
            if (writeE) *(floatx4*)&ebufW[(size_t)row * INDP + c0] = o;
        }
    }
}

__global__ __launch_bounds__(256)
void attn(const float* __restrict__ q, const float* __restrict__ k,
          const float* __restrict__ v, float* __restrict__ ao) {
    __shared__ float qs[TT][DH], ks[TT][DH], vs[TT][DH];
    __shared__ float sc[TT][TT + 1];
    int bh = blockIdx.x;
    int b = bh >> 2, h = bh & 3;
    int tid = threadIdx.x;
    for (int i = tid; i < TT * DH; i += 256) {
        int r = i / DH, d = i - r * DH;
        size_t base = (size_t)(b * TT + r) * FEAT + h * DH + d;
        qs[r][d] = q[base]; ks[r][d] = k[base]; vs[r][d] = v[base];
    }
    __syncthreads();
    const float scale = 0.11180339887498949f;   // 1/sqrt(80)
    for (int idx = tid; idx < TT * TT; idx += 256) {
        int i = idx >> 6, j = idx & 63;
        float s = 0.f;
        for (int d = 0; d < DH; ++d) s += qs[i][d] * ks[j][d];
        sc[i][j] = s * scale;
    }
    __syncthreads();
    if (tid < TT) {
        int i = tid;
        if (i == 0) {
            for (int j = 0; j < TT; ++j) sc[0][j] = 0.0f;
        } else {
            float m = -1e30f;
            for (int j = 0; j < i; ++j) m = fmaxf(m, sc[i][j]);
            float sum = 0.f;
            for (int j = 0; j < i; ++j) { float p = __expf(sc[i][j] - m); sc[i][j] = p; sum += p; }
            float inv = 1.0f / sum;
            for (int j = 0; j < i; ++j) sc[i][j] *= inv;
            for (int j = i; j < TT; ++j) sc[i][j] = 0.0f;
        }
    }
    __syncthreads();
    for (int idx = tid; idx < TT * DH; idx += 256) {
        int i = idx / DH, d = idx - i * DH;
        float s = 0.f;
        for (int j = 0; j < TT; ++j) s += sc[i][j] * vs[j][d];
        ao[(size_t)(b * TT + i) * FEAT + h * DH + d] = s;
    }
}

__global__ __launch_bounds__(128)
void score_k(const float* __restrict__ x, const float* __restrict__ W1,
             const float* __restrict__ b1, const float* __restrict__ W2,
             const float* __restrict__ b2, float* __restrict__ lam_out,
             float* __restrict__ loss_out) {
    __shared__ float xr[FEAT];
    __shared__ float red[2];
    int e = blockIdx.x;
    int tid = threadIdx.x;
    for (int f = tid; f < FEAT; f += 128) xr[f] = x[(size_t)e * FEAT + f];
    __syncthreads();
    int d = tid;
    float acc = b1[d];
    for (int kk = 0; kk < FEAT; ++kk) acc += xr[kk] * W1[kk * DD + d];
    acc = fmaxf(acc, 0.0f) * W2[d];
    for (int off = 32; off; off >>= 1) acc += __shfl_down(acc, off, 64);
    if ((tid & 63) == 0) red[tid >> 6] = acc;
    __syncthreads();
    if (tid == 0) {
        float s = red[0] + red[1] + b2[0];
        float lam = fmaxf(s, 0.0f) + log1pf(expf(-fabsf(s)));   // softplus
        lam_out[e] = lam;
        atomicAdd(loss_out, -logf(lam + 1e-8f) * (1.0f / 2048.0f));
    }
}

// ---------------- launch ----------------
extern "C" void kernel_launch(void* const* d_in, const int* in_sizes, int n_in,
                              void* d_out, int out_size, void* d_ws, size_t ws_size,
                              hipStream_t stream) {
    const int*   seq_s = (const int*)d_in[0];
    const int*   seq_o = (const int*)d_in[1];
    const int*   seq_r = (const int*)d_in[2];
    const float* seq_t = (const float*)d_in[3];
    const float* mem0  = (const float*)d_in[4];
    const float* lt0   = (const float*)d_in[5];
    const float* rel   = (const float*)d_in[6];
    const float* W_hidden = (const float*)d_in[7];
    const float* W_hh  = (const float*)d_in[8];
    const float* W_st  = (const float*)d_in[9];
    const float* W_ot  = (const float*)d_in[10];
    const float* Wq    = (const float*)d_in[11];
    const float* Wk    = (const float*)d_in[12];
    const float* Wv    = (const float*)d_in[13];
    const float* Wo    = (const float*)d_in[14];
    const float* sW1   = (const float*)d_in[15];
    const float* sb1   = (const float*)d_in[16];
    const float* sW2   = (const float*)d_in[17];
    const float* sb2   = (const float*)d_in[18];

    float* out      = (float*)d_out;
    float* out_lam  = out + 1;
    float* out_mem  = out + 2049;
    float* out_lt   = out + 2049 + (size_t)NE * DD;

    float* ws = (float*)d_ws;
    float* evt   = ws;                         // 655360
    float* xbuf  = ws + 655360;                // 655360
    float* ebuf  = ws + 1310720;               // 2048*512 = 1048576
    float* qbuf  = ws + 2359296;               // 655360
    float* kbuf  = ws + 3014656;               // 655360
    float* vbuf  = ws + 3670016;               // 655360
    float* aobuf = ws + 4325376;               // 655360
    float* slotDt   = ws + 4980736;            // 4096
    int*   slotPrev = (int*)(ws + 4984832);    // 4096
    int*   slotWin  = (int*)(ws + 4988928);    // 4096
    int*   fixList  = (int*)(ws + 4993024);    // 2048
    int*   fixState = (int*)(ws + 4995072);    // 2048
    int*   evFixIdx = (int*)(ws + 4997120);    // 2048
    int*   fixCnt   = (int*)(ws + 4999168);    // 1

    hipMemsetAsync(fixCnt, 0, sizeof(int), stream);
    hipMemsetAsync(out, 0, sizeof(float), stream);
    hipMemsetAsync(ebuf, 0, (size_t)NEV * INDP * sizeof(float), stream);   // zero K-pad cols

    copy_init<<<2048, 256, 0, stream>>>(mem0, lt0, out_mem, out_lt);

    slot_analyze<<<NSLOT / 4, 256, 0, stream>>>(seq_s, seq_o, seq_t, lt0,
                                                slotDt, slotPrev, slotWin);
    fixlist_build<<<NEV / 256, 256, 0, stream>>>(slotPrev, fixList, fixState,
                                                 evFixIdx, fixCnt);
    event_compute<<<NEV / 8, 256, 0, stream>>>(seq_s, seq_o, seq_r, seq_t, mem0, rel,
                                               W_hidden, W_hh, W_st, W_ot, slotDt,
                                               evt, ebuf);
    for (int r = 0; r < 4; ++r)
        fix_round<<<64, 256, 0, stream>>>(r, seq_s, seq_o, mem0, W_hidden, W_hh,
                                          W_st, W_ot, slotDt, slotPrev,
                                          fixList, fixState, evFixIdx, fixCnt, evt, ebuf);
    scatter_win<<<512, 256, 0, stream>>>(seq_s, seq_o, seq_t, slotWin, evt, out_mem, out_lt);

    for (int l = 0; l < 2; ++l) {
        const float* src = l ? xbuf : evt;     // residual input
        proj<<<dim3(64, 10, 3), 128, 0, stream>>>(ebuf,
                                                  Wq + (size_t)l * IND * FEAT,
                                                  Wk + (size_t)l * IND * FEAT,
                                                  Wv + (size_t)l * IND * FEAT,
                                                  qbuf, kbuf, vbuf);
        attn<<<128, 256, 0, stream>>>(qbuf, kbuf, vbuf, aobuf);
        outproj<<<dim3(64, 10), 128, 0, stream>>>(aobuf, Wo + (size_t)l * FEAT * FEAT,
                                                  src, xbuf, ebuf, (l == 0) ? 1 : 0);
    }
    score_k<<<NEV, 128, 0, stream>>>(xbuf, sW1, sb1, sW2, sb2, out_lam, out);
}